// Round 18
// baseline (326.669 us; speedup 1.0000x reference)
//
#include <hip/hip_runtime.h>

// ---------------------------------------------------------------------------
// GCN 2-layer: h1 = relu(LN(Ahat @ (x W1) + b1)); out = Ahat @ (h1 W2) + b2
// Ahat = D^-1/2 (A+I) D^-1/2, CSR built on-device each call (no feature atomics)
// R1: hierarchical scan. R2: LDS-tiled gemm. R3: pipelined gathers, bf16 table.
// R4: 4B edge payload. R6/7: packed (src<<16|bf16 w) payload, NT streams.
// R8: MFMA gemm. R9/10: padded CSR buckets, 16B descriptor batches.
// R11/12: named scalars (PromoteAlloca-to-LDS fix). R13: lookback scan
// REVERTED. R14: scan2 folded in (163.7). R16: 16-edge batches neutral.
// R5/R15: XCD feature-sharding x2: latency-bound gathers -> do not retry.
// R17: gemm1 || fill grid-mix (157.0). Fused dispatch = 43.5us, MFMA 1.3%,
//   WRITE 38MB vs 19 ideal -> fill's random 4B scatter into 6.4MB epk
//   (L2-overflow, partial-line thrash) is ~30us of it.
// R18: two-phase partition scatter. fill_a: append 8B records (payload +
//   dst|rank routing) to coarse dst>>6 buckets via atomic cursors (append =
//   full line use, 782 hot regions L2-resident); grid-mixed 1:4 with gemm1.
//   fill_b: per-bucket streaming re-scatter; each bucket's epk window ~5KB
//   -> writes coalesce. dinv moved into scan1.
// ---------------------------------------------------------------------------

typedef float f32x2 __attribute__((ext_vector_type(2)));
typedef float f32x4 __attribute__((ext_vector_type(4)));
typedef unsigned u32x2 __attribute__((ext_vector_type(2)));
typedef unsigned u32x4 __attribute__((ext_vector_type(4)));
typedef __bf16 bf16x8 __attribute__((ext_vector_type(8)));

#define CB_CAP 2048   // records per coarse bucket (mean ~1023 for n=50k,e=800k)

__device__ __forceinline__ unsigned short f2bf(float f) {
    unsigned u = __float_as_uint(f);
    u += 0x7FFF + ((u >> 16) & 1);     // round-to-nearest-even
    return (unsigned short)(u >> 16);
}
__device__ __forceinline__ float bfLo(unsigned g) { return __uint_as_float(g << 16); }
__device__ __forceinline__ float bfHi(unsigned g) { return __uint_as_float(g & 0xFFFF0000u); }

// W transpose->bf16 + cnt/ccur zero. One dispatch.
__global__ __launch_bounds__(256) void cvt_wi(const float* __restrict__ W1,
                                              const float* __restrict__ W2,
                                              unsigned short* __restrict__ W1t,
                                              unsigned short* __restrict__ W2t,
                                              int* __restrict__ cnt,
                                              int* __restrict__ ccur,
                                              int cbn, int n) {
    int id = blockIdx.x * 256 + threadIdx.x;
    if (id < 128 * 128) {
        int c = id >> 7, k = id & 127;
        W1t[id] = f2bf(W1[k * 128 + c]);
    } else if (id < 128 * 128 + 64 * 128) {
        int j = id - 128 * 128;
        int c = j >> 7, k = j & 127;
        W2t[j] = f2bf(W2[k * 64 + c]);
    }
    if (id < n) cnt[id] = 0;
    if (id < cbn) ccur[id] = 0;
}

// count + rank in one pass: rank = arrival order within dst bucket.
__global__ void count_k(const int* __restrict__ dst, int* __restrict__ cnt,
                        int* __restrict__ rank, int e) {
    int i = blockIdx.x * blockDim.x + threadIdx.x;
    if (i < e) {
        int r = atomicAdd(&cnt[dst[i]], 1);
        __builtin_nontemporal_store(r, &rank[i]);
    }
}

// Pass 1: per-block inclusive scan of ceil16(cnt) -> incl, block totals ->
// bsum; dinv computed here (unblocks fill_a earlier).
__global__ __launch_bounds__(1024) void scan1_k(const int* __restrict__ cnt,
                                                int* __restrict__ incl,
                                                int* __restrict__ bsum,
                                                float* __restrict__ dinv, int n) {
    __shared__ int lds[1024];
    int t = threadIdx.x;
    int i = blockIdx.x * 1024 + t;
    int c = (i < n) ? cnt[i] : 0;
    int v = (i < n) ? ((c + 15) & ~15) : 0;      // padded bucket size
    lds[t] = v;
    __syncthreads();
#pragma unroll
    for (int d = 1; d < 1024; d <<= 1) {
        int u = (t >= d) ? lds[t - d] : 0;
        __syncthreads();
        lds[t] += u;
        __syncthreads();
    }
    if (i < n) {
        incl[i] = lds[t];
        dinv[i] = rsqrtf((float)(c + 1));        // deg includes self loop
    }
    if (t == 1023) bsum[blockIdx.x] = lds[1023];
}

// Pass 2: offs (exclusive padded prefix), sentinel, pad-slot zeroing.
// Wave 0 re-scans bsum (nb <= 64) locally via shfl_up -> no 2nd scan dispatch.
__global__ __launch_bounds__(1024) void scan3_k(const int* __restrict__ cnt,
                                                const int* __restrict__ incl,
                                                const int* __restrict__ bsum,
                                                int* __restrict__ offs,
                                                unsigned* __restrict__ epk,
                                                int nb, int n) {
    __shared__ int sP;
    int t = threadIdx.x, bid = blockIdx.x;
    if (t < 64) {
        int raw = (t < nb) ? bsum[t] : 0;
        int v = raw;
#pragma unroll
        for (int d = 1; d < 64; d <<= 1) {
            int u = __shfl_up(v, d);
            if (t >= d) v += u;
        }
        if (t == bid) sP = v - raw;    // exclusive prefix of this block
    }
    __syncthreads();
    int i = bid * 1024 + t;
    if (i >= n) return;
    int c = cnt[i];
    int c16 = (c + 15) & ~15;
    int inc = sP + incl[i];            // inclusive padded prefix
    int ex = inc - c16;
    offs[i] = ex;
    for (int j = c; j < c16; ++j)      // zero pad slots (weight +0.0)
        __builtin_nontemporal_store(0u, &epk[ex + j]);
    if (i == n - 1) offs[n] = inc;
}

// Phase A of the scatter: append 8B record {payload, dst<<16|rank} to the
// dst>>6 coarse bucket. Appends fill 64B lines completely; 782 hot regions
// stay L2-resident -> no partial-line writeback thrash.
__device__ __forceinline__ void dev_fill_a(const int* __restrict__ src,
                                           const int* __restrict__ dst,
                                           const int* __restrict__ rank,
                                           const float* __restrict__ dinv,
                                           int* __restrict__ ccur,
                                           u32x2* __restrict__ cstage,
                                           int e, int bid) {
    int i = bid * 256 + threadIdx.x;
    if (i >= e) return;
    int s = src[i], d = dst[i], r = rank[i];
    float w = dinv[s] * dinv[d];       // in (0,1], sign bit 0 -> bf16 fits 16b
    int cb = d >> 6;
    int pos = atomicAdd(&ccur[cb], 1);
    u32x2 rec;
    rec.x = ((unsigned)s << 16) | (unsigned)f2bf(w);   // final epk payload
    rec.y = ((unsigned)d << 16) | (unsigned)r;         // routing
    cstage[(size_t)cb * CB_CAP + pos] = rec;
}

// Phase B: one block per coarse bucket; stream records, scatter payloads to
// epk[offs[dst]+rank]. Bucket's 64 nodes -> ~5KB contiguous epk window and a
// 256B offs slice -> fully cache-resident, writes coalesce.
__global__ __launch_bounds__(256) void fill_b(const u32x2* __restrict__ cstage,
                                              const int* __restrict__ ccur,
                                              const int* __restrict__ offs,
                                              unsigned* __restrict__ epk) {
    int cb = blockIdx.x;
    int cnt = ccur[cb];
    const u32x2* base = cstage + (size_t)cb * CB_CAP;
    for (int j = threadIdx.x; j < cnt; j += 256) {
        u32x2 rec = base[j];
        unsigned d = rec.y >> 16, r = rec.y & 0xFFFFu;
        epk[offs[d] + r] = rec.x;
    }
}

// MFMA GEMM body: A (bf16 [n][128], or f32 converted during staging when CVT)
// @ Wt^T (bf16 [NT*16][128] k-contiguous) -> tab (bf16 [n][NT*16]).
// Block = 64 rows, 4 waves. D layout (m89): col = lane&15, row = 4*(lane>>4)+reg.
template<int NT, bool CVT>
__device__ __forceinline__ void dev_gemm(const void* __restrict__ Asrc,
                                         const uint4* __restrict__ Wt,
                                         unsigned short* __restrict__ tab,
                                         int n, int bid, uint4* As) {
    int t = threadIdx.x;
    int r0 = bid * 64;
    int rows = min(64, n - r0);
#pragma unroll
    for (int it = 0; it < 4; ++it) {
        int u = it * 256 + t;
        int row = u >> 4, s = u & 15;
        uint4 v = make_uint4(0u, 0u, 0u, 0u);
        if (row < rows) {
            if constexpr (CVT) {
                const float4* X4 = (const float4*)Asrc;
                float4 a = X4[(size_t)(r0 + row) * 32 + 2 * s];
                float4 b = X4[(size_t)(r0 + row) * 32 + 2 * s + 1];
                v.x = (unsigned)f2bf(a.x) | ((unsigned)f2bf(a.y) << 16);
                v.y = (unsigned)f2bf(a.z) | ((unsigned)f2bf(a.w) << 16);
                v.z = (unsigned)f2bf(b.x) | ((unsigned)f2bf(b.y) << 16);
                v.w = (unsigned)f2bf(b.z) | ((unsigned)f2bf(b.w) << 16);
            } else {
                v = ((const uint4*)Asrc)[(size_t)(r0 + row) * 16 + s];
            }
        }
        As[row * 16 + (s ^ (row & 7))] = v;
    }
    __syncthreads();

    int wv = t >> 6, lane = t & 63;
    int arow = lane & 15;            // A-row within stripe / B-col within tile
    int kg = lane >> 4;              // k-group (frags) / row-group (D)
    int lrow = wv * 16 + arow;

    f32x4 acc[NT];
    f32x4 z = {0.f, 0.f, 0.f, 0.f};
#pragma unroll
    for (int j = 0; j < NT; ++j) acc[j] = z;

#pragma unroll
    for (int ks = 0; ks < 4; ++ks) {
        bf16x8 a = __builtin_bit_cast(bf16x8,
                       As[lrow * 16 + ((ks * 4 + kg) ^ (arow & 7))]);
#pragma unroll
        for (int tl = 0; tl < NT; ++tl) {
            bf16x8 b = __builtin_bit_cast(bf16x8,
                           Wt[(size_t)(tl * 16 + arow) * 16 + ks * 4 + kg]);
            acc[tl] = __builtin_amdgcn_mfma_f32_16x16x32_bf16(a, b, acc[tl], 0, 0, 0);
        }
    }

    int grow0 = r0 + wv * 16 + 4 * kg;
#pragma unroll
    for (int r = 0; r < 4; ++r) {
        int grow = grow0 + r;
        if (grow < n) {
            unsigned short* rowp = tab + (size_t)grow * (NT * 16) + arow;
#pragma unroll
            for (int tl = 0; tl < NT; ++tl)
                rowp[tl * 16] = f2bf(acc[tl][r]);
        }
    }
}

// Mixed dispatch: interleave gemm1 (every 5th block) with fill_a so both
// start immediately (gemm:fill block ratio ~1:4). Disjoint outputs; deps:
// gemm1 <- cvt_wi(W1t); fill_a <- scan1(dinv) + cvt_wi(ccur).
__global__ __launch_bounds__(256) void fill_gemm1_k(const float* __restrict__ x,
                                                    const uint4* __restrict__ W1t,
                                                    unsigned short* __restrict__ h0b,
                                                    int n, int gb,
                                                    const int* __restrict__ src,
                                                    const int* __restrict__ dst,
                                                    const int* __restrict__ rank,
                                                    const float* __restrict__ dinv,
                                                    int* __restrict__ ccur,
                                                    u32x2* __restrict__ cstage, int e) {
    __shared__ uint4 As[64 * 16];   // 16 KB (gemm path only)
    int bid = blockIdx.x;
    int g = bid / 5, r = bid % 5;
    if (r == 0 && g < gb)
        dev_gemm<8, true>(x, W1t, h0b, n, g, As);
    else
        dev_fill_a(src, dst, rank, dinv, ccur, cstage, e, g * 4 + r - 1);
}

// gemm2: h1b bf16 @ W2t -> h2 bf16 table.
__global__ __launch_bounds__(256) void gemm2_k(const unsigned* __restrict__ h1b,
                                               const uint4* __restrict__ W2t,
                                               unsigned short* __restrict__ tab,
                                               int n) {
    __shared__ uint4 As[64 * 16];
    dev_gemm<4, false>(h1b, W2t, tab, n, blockIdx.x, As);
}

// Layer 1 propagation + bias + LayerNorm + ReLU. One wave per node, lane
// holds features {2*lane, 2*lane+1}. Buckets padded to x16: per iteration
// 4x 16B NT descriptor loads + 16 independent gathers in flight, all named
// scalars (no local arrays -> no PromoteAlloca-to-LDS).
__global__ __launch_bounds__(256) void prop_ln(const unsigned* __restrict__ h0b,
                                               const int* __restrict__ offs,
                                               const unsigned* __restrict__ epk,
                                               const float* __restrict__ dinv,
                                               const float* __restrict__ b1,
                                               const float* __restrict__ gamma,
                                               const float* __restrict__ beta,
                                               unsigned* __restrict__ h1b, int n) {
    int wid = __builtin_amdgcn_readfirstlane((blockIdx.x * blockDim.x + threadIdx.x) >> 6);
    int lane = threadIdx.x & 63;
    if (wid >= n) return;
    float di = dinv[wid];
    unsigned self = h0b[(size_t)wid * 64 + lane];
    float a0 = bfLo(self) * di * di;   // self loop, norm = dinv^2
    float a1 = bfHi(self) * di * di;

    int s0 = offs[wid], s1 = offs[wid + 1];
    if (s0 < s1) {
        const u32x4* ep4 = (const u32x4*)(epk + s0);   // 64B-aligned (offs % 16 == 0)
        int nb16 = (s1 - s0) >> 4;
        u32x4 d0 = __builtin_nontemporal_load(ep4);
        u32x4 d1 = __builtin_nontemporal_load(ep4 + 1);
        u32x4 d2 = __builtin_nontemporal_load(ep4 + 2);
        u32x4 d3 = __builtin_nontemporal_load(ep4 + 3);
        for (int b = 0; b < nb16; ++b) {
            unsigned g0  = h0b[(size_t)(d0.x >> 16) * 64 + lane];
            unsigned g1  = h0b[(size_t)(d0.y >> 16) * 64 + lane];
            unsigned g2  = h0b[(size_t)(d0.z >> 16) * 64 + lane];
            unsigned g3  = h0b[(size_t)(d0.w >> 16) * 64 + lane];
            unsigned g4  = h0b[(size_t)(d1.x >> 16) * 64 + lane];
            unsigned g5  = h0b[(size_t)(d1.y >> 16) * 64 + lane];
            unsigned g6  = h0b[(size_t)(d1.z >> 16) * 64 + lane];
            unsigned g7  = h0b[(size_t)(d1.w >> 16) * 64 + lane];
            unsigned g8  = h0b[(size_t)(d2.x >> 16) * 64 + lane];
            unsigned g9  = h0b[(size_t)(d2.y >> 16) * 64 + lane];
            unsigned g10 = h0b[(size_t)(d2.z >> 16) * 64 + lane];
            unsigned g11 = h0b[(size_t)(d2.w >> 16) * 64 + lane];
            unsigned g12 = h0b[(size_t)(d3.x >> 16) * 64 + lane];
            unsigned g13 = h0b[(size_t)(d3.y >> 16) * 64 + lane];
            unsigned g14 = h0b[(size_t)(d3.z >> 16) * 64 + lane];
            unsigned g15 = h0b[(size_t)(d3.w >> 16) * 64 + lane];
            float w0  = bfLo(d0.x), w1  = bfLo(d0.y), w2  = bfLo(d0.z), w3  = bfLo(d0.w);
            float w4  = bfLo(d1.x), w5  = bfLo(d1.y), w6  = bfLo(d1.z), w7  = bfLo(d1.w);
            float w8  = bfLo(d2.x), w9  = bfLo(d2.y), w10 = bfLo(d2.z), w11 = bfLo(d2.w);
            float w12 = bfLo(d3.x), w13 = bfLo(d3.y), w14 = bfLo(d3.z), w15 = bfLo(d3.w);
            int bn = (b + 1 < nb16) ? b + 1 : 0;       // wave-uniform select
            d0 = __builtin_nontemporal_load(ep4 + 4 * bn);
            d1 = __builtin_nontemporal_load(ep4 + 4 * bn + 1);
            d2 = __builtin_nontemporal_load(ep4 + 4 * bn + 2);
            d3 = __builtin_nontemporal_load(ep4 + 4 * bn + 3);
            a0 = fmaf(bfLo(g0),  w0,  a0); a1 = fmaf(bfHi(g0),  w0,  a1);
            a0 = fmaf(bfLo(g1),  w1,  a0); a1 = fmaf(bfHi(g1),  w1,  a1);
            a0 = fmaf(bfLo(g2),  w2,  a0); a1 = fmaf(bfHi(g2),  w2,  a1);
            a0 = fmaf(bfLo(g3),  w3,  a0); a1 = fmaf(bfHi(g3),  w3,  a1);
            a0 = fmaf(bfLo(g4),  w4,  a0); a1 = fmaf(bfHi(g4),  w4,  a1);
            a0 = fmaf(bfLo(g5),  w5,  a0); a1 = fmaf(bfHi(g5),  w5,  a1);
            a0 = fmaf(bfLo(g6),  w6,  a0); a1 = fmaf(bfHi(g6),  w6,  a1);
            a0 = fmaf(bfLo(g7),  w7,  a0); a1 = fmaf(bfHi(g7),  w7,  a1);
            a0 = fmaf(bfLo(g8),  w8,  a0); a1 = fmaf(bfHi(g8),  w8,  a1);
            a0 = fmaf(bfLo(g9),  w9,  a0); a1 = fmaf(bfHi(g9),  w9,  a1);
            a0 = fmaf(bfLo(g10), w10, a0); a1 = fmaf(bfHi(g10), w10, a1);
            a0 = fmaf(bfLo(g11), w11, a0); a1 = fmaf(bfHi(g11), w11, a1);
            a0 = fmaf(bfLo(g12), w12, a0); a1 = fmaf(bfHi(g12), w12, a1);
            a0 = fmaf(bfLo(g13), w13, a0); a1 = fmaf(bfHi(g13), w13, a1);
            a0 = fmaf(bfLo(g14), w14, a0); a1 = fmaf(bfHi(g14), w14, a1);
            a0 = fmaf(bfLo(g15), w15, a0); a1 = fmaf(bfHi(g15), w15, a1);
        }
    }

    a0 += b1[2 * lane];
    a1 += b1[2 * lane + 1];
    // LayerNorm over 128 features spread across the 64-lane wave
    float sum = a0 + a1, sq = a0 * a0 + a1 * a1;
#pragma unroll
    for (int off = 32; off > 0; off >>= 1) {
        sum += __shfl_xor(sum, off);
        sq  += __shfl_xor(sq, off);
    }
    float mu  = sum * (1.f / 128.f);
    float var = fmaxf(sq * (1.f / 128.f) - mu * mu, 0.f);
    float rstd = rsqrtf(var + 1e-6f);
    float y0 = fmaxf((a0 - mu) * rstd * gamma[2 * lane] + beta[2 * lane], 0.f);
    float y1 = fmaxf((a1 - mu) * rstd * gamma[2 * lane + 1] + beta[2 * lane + 1], 0.f);
    unsigned pk = (unsigned)f2bf(y0) | ((unsigned)f2bf(y1) << 16);
    __builtin_nontemporal_store(pk, &h1b[(size_t)wid * 64 + lane]);
}

// Layer 2 propagation + bias. One wave per node; 2 edges per gather
// instruction (es = lane>>5 picks edge 2j+es, u = lane&31 is the uint chunk
// of the 64-feature row). 16-edge batches -> 8 gathers in flight per lane.
__global__ __launch_bounds__(256) void prop_out(const unsigned* __restrict__ h2b,
                                                const int* __restrict__ offs,
                                                const unsigned* __restrict__ epk,
                                                const float* __restrict__ dinv,
                                                const float* __restrict__ b2,
                                                float* __restrict__ out, int n) {
    int wid = __builtin_amdgcn_readfirstlane((blockIdx.x * blockDim.x + threadIdx.x) >> 6);
    int lane = threadIdx.x & 63;
    if (wid >= n) return;
    int es = lane >> 5, u = lane & 31;
    float di = dinv[wid];
    float a0 = 0.f, a1 = 0.f;
    if (es == 0) {
        unsigned self = h2b[(size_t)wid * 32 + u];
        a0 = bfLo(self) * di * di;
        a1 = bfHi(self) * di * di;
    }

    int s0 = offs[wid], s1 = offs[wid + 1];
    if (s0 < s1) {
        const u32x4* ep4 = (const u32x4*)(epk + s0);
        int nb16 = (s1 - s0) >> 4;
        u32x4 d0 = __builtin_nontemporal_load(ep4);
        u32x4 d1 = __builtin_nontemporal_load(ep4 + 1);
        u32x4 d2 = __builtin_nontemporal_load(ep4 + 2);
        u32x4 d3 = __builtin_nontemporal_load(ep4 + 3);
        for (int b = 0; b < nb16; ++b) {
            unsigned dd0 = es ? d0.y : d0.x;
            unsigned dd1 = es ? d0.w : d0.z;
            unsigned dd2 = es ? d1.y : d1.x;
            unsigned dd3 = es ? d1.w : d1.z;
            unsigned dd4 = es ? d2.y : d2.x;
            unsigned dd5 = es ? d2.w : d2.z;
            unsigned dd6 = es ? d3.y : d3.x;
            unsigned dd7 = es ? d3.w : d3.z;
            unsigned g0 = h2b[(size_t)(dd0 >> 16) * 32 + u];
            unsigned g1 = h2b[(size_t)(dd1 >> 16) * 32 + u];
            unsigned g2 = h2b[(size_t)(dd2 >> 16) * 32 + u];
            unsigned g3 = h2b[(size_t)(dd3 >> 16) * 32 + u];
            unsigned g4 = h2b[(size_t)(dd4 >> 16) * 32 + u];
            unsigned g5 = h2b[(size_t)(dd5 >> 16) * 32 + u];
            unsigned g6 = h2b[(size_t)(dd6 >> 16) * 32 + u];
            unsigned g7 = h2b[(size_t)(dd7 >> 16) * 32 + u];
            float w0 = bfLo(dd0), w1 = bfLo(dd1), w2 = bfLo(dd2), w3 = bfLo(dd3);
            float w4 = bfLo(dd4), w5 = bfLo(dd5), w6 = bfLo(dd6), w7 = bfLo(dd7);
            int bn = (b + 1 < nb16) ? b + 1 : 0;
            d0 = __builtin_nontemporal_load(ep4 + 4 * bn);
            d1 = __builtin_nontemporal_load(ep4 + 4 * bn + 1);
            d2 = __builtin_nontemporal_load(ep4 + 4 * bn + 2);
            d3 = __builtin_nontemporal_load(ep4 + 4 * bn + 3);
            a0 = fmaf(bfLo(g0), w0, a0); a1 = fmaf(bfHi(g0), w0, a1);
            a0 = fmaf(bfLo(g1), w1, a0); a1 = fmaf(bfHi(g1), w1, a1);
            a0 = fmaf(bfLo(g2), w2, a0); a1 = fmaf(bfHi(g2), w2, a1);
            a0 = fmaf(bfLo(g3), w3, a0); a1 = fmaf(bfHi(g3), w3, a1);
            a0 = fmaf(bfLo(g4), w4, a0); a1 = fmaf(bfHi(g4), w4, a1);
            a0 = fmaf(bfLo(g5), w5, a0); a1 = fmaf(bfHi(g5), w5, a1);
            a0 = fmaf(bfLo(g6), w6, a0); a1 = fmaf(bfHi(g6), w6, a1);
            a0 = fmaf(bfLo(g7), w7, a0); a1 = fmaf(bfHi(g7), w7, a1);
        }
    }

    a0 += __shfl_xor(a0, 32);
    a1 += __shfl_xor(a1, 32);
    if (es == 0) {
        f32x2 o; o.x = a0 + b2[2 * u]; o.y = a1 + b2[2 * u + 1];
        __builtin_nontemporal_store(o, &((f32x2*)out)[(size_t)wid * 32 + u]);
    }
}

extern "C" void kernel_launch(void* const* d_in, const int* in_sizes, int n_in,
                              void* d_out, int out_size, void* d_ws, size_t ws_size,
                              hipStream_t stream) {
    const float* x     = (const float*)d_in[0];
    const int*   ei    = (const int*)d_in[1];
    const float* W1    = (const float*)d_in[2];
    const float* b1    = (const float*)d_in[3];
    const float* gam   = (const float*)d_in[4];
    const float* bet   = (const float*)d_in[5];
    const float* W2    = (const float*)d_in[6];
    const float* b2    = (const float*)d_in[7];
    float* out = (float*)d_out;

    int n = in_sizes[0] / 128;   // 50000  (must stay < 65536 for packed src/dst)
    int e = in_sizes[1] / 2;     // 800000
    const int* src = ei;
    const int* dst = ei + e;
    size_t ecap = (size_t)e + 16 * (size_t)n;   // padded CSR capacity
    int cbn = (n + 63) >> 6;                    // coarse buckets (782)

    char* p = (char*)d_ws;
    auto alloc = [&](size_t bytes) {
        void* q = (void*)p;
        p += (bytes + 255) & ~(size_t)255;
        return q;
    };
    int*            cnt    = (int*)alloc((size_t)n * 4);
    int*            offs   = (int*)alloc((size_t)(n + 1) * 4);
    int*            rank   = (int*)alloc((size_t)e * 4);
    float*          dinv   = (float*)alloc((size_t)n * 4);
    int*            incl   = (int*)alloc((size_t)n * 4);
    int*            bsum   = (int*)alloc(64 * 4);
    int*            ccur   = (int*)alloc((size_t)cbn * 4);
    u32x2*          cstage = (u32x2*)alloc((size_t)cbn * CB_CAP * 8);  // 12.8MB
    unsigned*       epk    = (unsigned*)alloc(ecap * 4);
    unsigned*       h0b    = (unsigned*)alloc((size_t)n * 64 * 4);  // bf16 [n][128]
    unsigned*       h1b    = (unsigned*)alloc((size_t)n * 64 * 4);  // bf16 [n][128]
    unsigned short* W1t    = (unsigned short*)alloc(128 * 128 * 2);
    unsigned short* W2t    = (unsigned short*)alloc(64 * 128 * 2);

    // Layer-2 table [n][32] aliases h0b (h0b dead after prop_ln).
    unsigned* h2b = h0b;

    int nb = (n + 1023) / 1024;  // 49 blocks for n=50000
    int gb = (n + 63) / 64;      // 782 gemm blocks

    cvt_wi<<<(n + 255) / 256, 256, 0, stream>>>(W1, W2, W1t, W2t, cnt, ccur, cbn, n);
    count_k<<<(e + 255) / 256, 256, 0, stream>>>(dst, cnt, rank, e);
    scan1_k<<<nb, 1024, 0, stream>>>(cnt, incl, bsum, dinv, n);
    scan3_k<<<nb, 1024, 0, stream>>>(cnt, incl, bsum, offs, epk, nb, n);
    fill_gemm1_k<<<gb * 5, 256, 0, stream>>>(x, (const uint4*)W1t,
                                             (unsigned short*)h0b, n, gb,
                                             src, dst, rank, dinv, ccur, cstage, e);
    fill_b<<<cbn, 256, 0, stream>>>(cstage, ccur, offs, epk);
    prop_ln<<<(n + 3) / 4, 256, 0, stream>>>(h0b, offs, epk, dinv, b1, gam, bet, h1b, n);
    gemm2_k<<<gb, 256, 0, stream>>>(h1b, (const uint4*)W2t,
                                    (unsigned short*)h2b, n);
    prop_out<<<(n + 3) / 4, 256, 0, stream>>>(h2b, offs, epk, dinv, b2, out, n);
}

// Round 19
// 161.536 us; speedup vs baseline: 2.0223x; 2.0223x over previous
//
#include <hip/hip_runtime.h>

// ---------------------------------------------------------------------------
// GCN 2-layer: h1 = relu(LN(Ahat @ (x W1) + b1)); out = Ahat @ (h1 W2) + b2
// Ahat = D^-1/2 (A+I) D^-1/2, CSR built on-device each call (no feature atomics)
// R1: hierarchical scan. R2: LDS-tiled gemm. R3: pipelined gathers, bf16 table.
// R4: 4B edge payload. R6/7: packed (src<<16|bf16 w) payload, NT streams.
// R8: MFMA gemm. R9/10: padded CSR buckets, 16B descriptor batches.
// R11/12: named scalars (PromoteAlloca-to-LDS fix). R14: folded scan (163.7).
// R16: 16-edge batches neutral (MSHR-saturated). R17: gemm1||fill grid-mix
//   (157.0 = best).
// FAILED & DO-NOT-RETRY: R13 lookback scan (serial atomic chain);
//   R5/R15 XCD feature-sharding (gathers latency-bound, sharding multiplies
//   loop work); R18 atomic-append partition scatter (cursor fetch-add chains
//   serialize + cstage append re-creates partial-line thrash at 2x bytes).
// R19: revert to R17; fused dispatch only: (a) 1:4 gemm:fill block interleave
//   (both co-resident from t=0), (b) NT store for the epk scatter (skip RFO
//   write-allocate on once-written lines).
// ---------------------------------------------------------------------------

typedef float f32x2 __attribute__((ext_vector_type(2)));
typedef float f32x4 __attribute__((ext_vector_type(4)));
typedef unsigned u32x4 __attribute__((ext_vector_type(4)));
typedef __bf16 bf16x8 __attribute__((ext_vector_type(8)));

__device__ __forceinline__ unsigned short f2bf(float f) {
    unsigned u = __float_as_uint(f);
    u += 0x7FFF + ((u >> 16) & 1);     // round-to-nearest-even
    return (unsigned short)(u >> 16);
}
__device__ __forceinline__ float bfLo(unsigned g) { return __uint_as_float(g << 16); }
__device__ __forceinline__ float bfHi(unsigned g) { return __uint_as_float(g & 0xFFFF0000u); }

// W transpose->bf16 + cnt zero. One dispatch.
__global__ __launch_bounds__(256) void cvt_wi(const float* __restrict__ W1,
                                              const float* __restrict__ W2,
                                              unsigned short* __restrict__ W1t,
                                              unsigned short* __restrict__ W2t,
                                              int* __restrict__ cnt, int n) {
    int id = blockIdx.x * 256 + threadIdx.x;
    if (id < 128 * 128) {
        int c = id >> 7, k = id & 127;
        W1t[id] = f2bf(W1[k * 128 + c]);
    } else if (id < 128 * 128 + 64 * 128) {
        int j = id - 128 * 128;
        int c = j >> 7, k = j & 127;
        W2t[j] = f2bf(W2[k * 64 + c]);
    }
    if (id < n) cnt[id] = 0;
}

// count + rank in one pass: rank = arrival order within dst bucket.
__global__ void count_k(const int* __restrict__ dst, int* __restrict__ cnt,
                        int* __restrict__ rank, int e) {
    int i = blockIdx.x * blockDim.x + threadIdx.x;
    if (i < e) {
        int r = atomicAdd(&cnt[dst[i]], 1);
        __builtin_nontemporal_store(r, &rank[i]);
    }
}

// Pass 1: per-block inclusive scan of ceil16(cnt) -> incl, block totals ->
// bsum; dinv computed here.
__global__ __launch_bounds__(1024) void scan1_k(const int* __restrict__ cnt,
                                                int* __restrict__ incl,
                                                int* __restrict__ bsum,
                                                float* __restrict__ dinv, int n) {
    __shared__ int lds[1024];
    int t = threadIdx.x;
    int i = blockIdx.x * 1024 + t;
    int c = (i < n) ? cnt[i] : 0;
    int v = (i < n) ? ((c + 15) & ~15) : 0;      // padded bucket size
    lds[t] = v;
    __syncthreads();
#pragma unroll
    for (int d = 1; d < 1024; d <<= 1) {
        int u = (t >= d) ? lds[t - d] : 0;
        __syncthreads();
        lds[t] += u;
        __syncthreads();
    }
    if (i < n) {
        incl[i] = lds[t];
        dinv[i] = rsqrtf((float)(c + 1));        // deg includes self loop
    }
    if (t == 1023) bsum[blockIdx.x] = lds[1023];
}

// Pass 2: offs (exclusive padded prefix), sentinel, pad-slot zeroing.
// Wave 0 re-scans bsum (nb <= 64) locally via shfl_up -> no 2nd scan dispatch.
__global__ __launch_bounds__(1024) void scan3_k(const int* __restrict__ cnt,
                                                const int* __restrict__ incl,
                                                const int* __restrict__ bsum,
                                                int* __restrict__ offs,
                                                unsigned* __restrict__ epk,
                                                int nb, int n) {
    __shared__ int sP;
    int t = threadIdx.x, bid = blockIdx.x;
    if (t < 64) {
        int raw = (t < nb) ? bsum[t] : 0;
        int v = raw;
#pragma unroll
        for (int d = 1; d < 64; d <<= 1) {
            int u = __shfl_up(v, d);
            if (t >= d) v += u;
        }
        if (t == bid) sP = v - raw;    // exclusive prefix of this block
    }
    __syncthreads();
    int i = bid * 1024 + t;
    if (i >= n) return;
    int c = cnt[i];
    int c16 = (c + 15) & ~15;
    int inc = sP + incl[i];            // inclusive padded prefix
    int ex = inc - c16;
    offs[i] = ex;
    for (int j = c; j < c16; ++j)      // zero pad slots (weight +0.0)
        __builtin_nontemporal_store(0u, &epk[ex + j]);
    if (i == n - 1) offs[n] = inc;
}

// Scatter packed (src<<16 | bf16(w)) into CSR slots. 4B payload, no atomics.
// NT store: line is written once here and next touched by prop_ln's stream.
__device__ __forceinline__ void dev_fill(const int* __restrict__ src,
                                         const int* __restrict__ dst,
                                         const int* __restrict__ rank,
                                         const int* __restrict__ offs,
                                         const float* __restrict__ dinv,
                                         unsigned* __restrict__ epk, int e, int bid) {
    int i = bid * 256 + threadIdx.x;
    if (i >= e) return;
    int s = src[i], d = dst[i];
    float w = dinv[s] * dinv[d];         // in (0,1], sign bit 0 -> bf16 fits 16b
    unsigned pay = ((unsigned)s << 16) | (unsigned)f2bf(w);
    __builtin_nontemporal_store(pay, &epk[offs[d] + rank[i]]);
}

// MFMA GEMM body: A (bf16 [n][128], or f32 converted during staging when CVT)
// @ Wt^T (bf16 [NT*16][128] k-contiguous) -> tab (bf16 [n][NT*16]).
// Block = 64 rows, 4 waves. D layout (m89): col = lane&15, row = 4*(lane>>4)+reg.
template<int NT, bool CVT>
__device__ __forceinline__ void dev_gemm(const void* __restrict__ Asrc,
                                         const uint4* __restrict__ Wt,
                                         unsigned short* __restrict__ tab,
                                         int n, int bid, uint4* As) {
    int t = threadIdx.x;
    int r0 = bid * 64;
    int rows = min(64, n - r0);
#pragma unroll
    for (int it = 0; it < 4; ++it) {
        int u = it * 256 + t;
        int row = u >> 4, s = u & 15;
        uint4 v = make_uint4(0u, 0u, 0u, 0u);
        if (row < rows) {
            if constexpr (CVT) {
                const float4* X4 = (const float4*)Asrc;
                float4 a = X4[(size_t)(r0 + row) * 32 + 2 * s];
                float4 b = X4[(size_t)(r0 + row) * 32 + 2 * s + 1];
                v.x = (unsigned)f2bf(a.x) | ((unsigned)f2bf(a.y) << 16);
                v.y = (unsigned)f2bf(a.z) | ((unsigned)f2bf(a.w) << 16);
                v.z = (unsigned)f2bf(b.x) | ((unsigned)f2bf(b.y) << 16);
                v.w = (unsigned)f2bf(b.z) | ((unsigned)f2bf(b.w) << 16);
            } else {
                v = ((const uint4*)Asrc)[(size_t)(r0 + row) * 16 + s];
            }
        }
        As[row * 16 + (s ^ (row & 7))] = v;
    }
    __syncthreads();

    int wv = t >> 6, lane = t & 63;
    int arow = lane & 15;            // A-row within stripe / B-col within tile
    int kg = lane >> 4;              // k-group (frags) / row-group (D)
    int lrow = wv * 16 + arow;

    f32x4 acc[NT];
    f32x4 z = {0.f, 0.f, 0.f, 0.f};
#pragma unroll
    for (int j = 0; j < NT; ++j) acc[j] = z;

#pragma unroll
    for (int ks = 0; ks < 4; ++ks) {
        bf16x8 a = __builtin_bit_cast(bf16x8,
                       As[lrow * 16 + ((ks * 4 + kg) ^ (arow & 7))]);
#pragma unroll
        for (int tl = 0; tl < NT; ++tl) {
            bf16x8 b = __builtin_bit_cast(bf16x8,
                           Wt[(size_t)(tl * 16 + arow) * 16 + ks * 4 + kg]);
            acc[tl] = __builtin_amdgcn_mfma_f32_16x16x32_bf16(a, b, acc[tl], 0, 0, 0);
        }
    }

    int grow0 = r0 + wv * 16 + 4 * kg;
#pragma unroll
    for (int r = 0; r < 4; ++r) {
        int grow = grow0 + r;
        if (grow < n) {
            unsigned short* rowp = tab + (size_t)grow * (NT * 16) + arow;
#pragma unroll
            for (int tl = 0; tl < NT; ++tl)
                rowp[tl * 16] = f2bf(acc[tl][r]);
        }
    }
}

// Mixed dispatch, 1:4 interleave (gb gemm : 4*gb >= fb fill blocks): both
// workload types co-resident from t=0. Disjoint outputs; deps:
// gemm1 <- cvt_wi(W1t); fill <- scan1(dinv)+scan3(offs)+count(rank).
__global__ __launch_bounds__(256) void fill_gemm1_k(const float* __restrict__ x,
                                                    const uint4* __restrict__ W1t,
                                                    unsigned short* __restrict__ h0b,
                                                    int n, int gb,
                                                    const int* __restrict__ src,
                                                    const int* __restrict__ dst,
                                                    const int* __restrict__ rank,
                                                    const int* __restrict__ offs,
                                                    const float* __restrict__ dinv,
                                                    unsigned* __restrict__ epk, int e) {
    __shared__ uint4 As[64 * 16];   // 16 KB (gemm path only)
    int bid = blockIdx.x;
    int g = bid / 5, r = bid % 5;
    if (r == 0 && g < gb)
        dev_gemm<8, true>(x, W1t, h0b, n, g, As);
    else
        dev_fill(src, dst, rank, offs, dinv, epk, e, g * 4 + r - 1);
}

// gemm2: h1b bf16 @ W2t -> h2 bf16 table.
__global__ __launch_bounds__(256) void gemm2_k(const unsigned* __restrict__ h1b,
                                               const uint4* __restrict__ W2t,
                                               unsigned short* __restrict__ tab,
                                               int n) {
    __shared__ uint4 As[64 * 16];
    dev_gemm<4, false>(h1b, W2t, tab, n, blockIdx.x, As);
}

// Layer 1 propagation + bias + LayerNorm + ReLU. One wave per node, lane
// holds features {2*lane, 2*lane+1}. Buckets padded to x16: per iteration
// 4x 16B NT descriptor loads + 16 independent gathers in flight, all named
// scalars (no local arrays -> no PromoteAlloca-to-LDS).
__global__ __launch_bounds__(256) void prop_ln(const unsigned* __restrict__ h0b,
                                               const int* __restrict__ offs,
                                               const unsigned* __restrict__ epk,
                                               const float* __restrict__ dinv,
                                               const float* __restrict__ b1,
                                               const float* __restrict__ gamma,
                                               const float* __restrict__ beta,
                                               unsigned* __restrict__ h1b, int n) {
    int wid = __builtin_amdgcn_readfirstlane((blockIdx.x * blockDim.x + threadIdx.x) >> 6);
    int lane = threadIdx.x & 63;
    if (wid >= n) return;
    float di = dinv[wid];
    unsigned self = h0b[(size_t)wid * 64 + lane];
    float a0 = bfLo(self) * di * di;   // self loop, norm = dinv^2
    float a1 = bfHi(self) * di * di;

    int s0 = offs[wid], s1 = offs[wid + 1];
    if (s0 < s1) {
        const u32x4* ep4 = (const u32x4*)(epk + s0);   // 64B-aligned (offs % 16 == 0)
        int nb16 = (s1 - s0) >> 4;
        u32x4 d0 = __builtin_nontemporal_load(ep4);
        u32x4 d1 = __builtin_nontemporal_load(ep4 + 1);
        u32x4 d2 = __builtin_nontemporal_load(ep4 + 2);
        u32x4 d3 = __builtin_nontemporal_load(ep4 + 3);
        for (int b = 0; b < nb16; ++b) {
            unsigned g0  = h0b[(size_t)(d0.x >> 16) * 64 + lane];
            unsigned g1  = h0b[(size_t)(d0.y >> 16) * 64 + lane];
            unsigned g2  = h0b[(size_t)(d0.z >> 16) * 64 + lane];
            unsigned g3  = h0b[(size_t)(d0.w >> 16) * 64 + lane];
            unsigned g4  = h0b[(size_t)(d1.x >> 16) * 64 + lane];
            unsigned g5  = h0b[(size_t)(d1.y >> 16) * 64 + lane];
            unsigned g6  = h0b[(size_t)(d1.z >> 16) * 64 + lane];
            unsigned g7  = h0b[(size_t)(d1.w >> 16) * 64 + lane];
            unsigned g8  = h0b[(size_t)(d2.x >> 16) * 64 + lane];
            unsigned g9  = h0b[(size_t)(d2.y >> 16) * 64 + lane];
            unsigned g10 = h0b[(size_t)(d2.z >> 16) * 64 + lane];
            unsigned g11 = h0b[(size_t)(d2.w >> 16) * 64 + lane];
            unsigned g12 = h0b[(size_t)(d3.x >> 16) * 64 + lane];
            unsigned g13 = h0b[(size_t)(d3.y >> 16) * 64 + lane];
            unsigned g14 = h0b[(size_t)(d3.z >> 16) * 64 + lane];
            unsigned g15 = h0b[(size_t)(d3.w >> 16) * 64 + lane];
            float w0  = bfLo(d0.x), w1  = bfLo(d0.y), w2  = bfLo(d0.z), w3  = bfLo(d0.w);
            float w4  = bfLo(d1.x), w5  = bfLo(d1.y), w6  = bfLo(d1.z), w7  = bfLo(d1.w);
            float w8  = bfLo(d2.x), w9  = bfLo(d2.y), w10 = bfLo(d2.z), w11 = bfLo(d2.w);
            float w12 = bfLo(d3.x), w13 = bfLo(d3.y), w14 = bfLo(d3.z), w15 = bfLo(d3.w);
            int bn = (b + 1 < nb16) ? b + 1 : 0;       // wave-uniform select
            d0 = __builtin_nontemporal_load(ep4 + 4 * bn);
            d1 = __builtin_nontemporal_load(ep4 + 4 * bn + 1);
            d2 = __builtin_nontemporal_load(ep4 + 4 * bn + 2);
            d3 = __builtin_nontemporal_load(ep4 + 4 * bn + 3);
            a0 = fmaf(bfLo(g0),  w0,  a0); a1 = fmaf(bfHi(g0),  w0,  a1);
            a0 = fmaf(bfLo(g1),  w1,  a0); a1 = fmaf(bfHi(g1),  w1,  a1);
            a0 = fmaf(bfLo(g2),  w2,  a0); a1 = fmaf(bfHi(g2),  w2,  a1);
            a0 = fmaf(bfLo(g3),  w3,  a0); a1 = fmaf(bfHi(g3),  w3,  a1);
            a0 = fmaf(bfLo(g4),  w4,  a0); a1 = fmaf(bfHi(g4),  w4,  a1);
            a0 = fmaf(bfLo(g5),  w5,  a0); a1 = fmaf(bfHi(g5),  w5,  a1);
            a0 = fmaf(bfLo(g6),  w6,  a0); a1 = fmaf(bfHi(g6),  w6,  a1);
            a0 = fmaf(bfLo(g7),  w7,  a0); a1 = fmaf(bfHi(g7),  w7,  a1);
            a0 = fmaf(bfLo(g8),  w8,  a0); a1 = fmaf(bfHi(g8),  w8,  a1);
            a0 = fmaf(bfLo(g9),  w9,  a0); a1 = fmaf(bfHi(g9),  w9,  a1);
            a0 = fmaf(bfLo(g10), w10, a0); a1 = fmaf(bfHi(g10), w10, a1);
            a0 = fmaf(bfLo(g11), w11, a0); a1 = fmaf(bfHi(g11), w11, a1);
            a0 = fmaf(bfLo(g12), w12, a0); a1 = fmaf(bfHi(g12), w12, a1);
            a0 = fmaf(bfLo(g13), w13, a0); a1 = fmaf(bfHi(g13), w13, a1);
            a0 = fmaf(bfLo(g14), w14, a0); a1 = fmaf(bfHi(g14), w14, a1);
            a0 = fmaf(bfLo(g15), w15, a0); a1 = fmaf(bfHi(g15), w15, a1);
        }
    }

    a0 += b1[2 * lane];
    a1 += b1[2 * lane + 1];
    // LayerNorm over 128 features spread across the 64-lane wave
    float sum = a0 + a1, sq = a0 * a0 + a1 * a1;
#pragma unroll
    for (int off = 32; off > 0; off >>= 1) {
        sum += __shfl_xor(sum, off);
        sq  += __shfl_xor(sq, off);
    }
    float mu  = sum * (1.f / 128.f);
    float var = fmaxf(sq * (1.f / 128.f) - mu * mu, 0.f);
    float rstd = rsqrtf(var + 1e-6f);
    float y0 = fmaxf((a0 - mu) * rstd * gamma[2 * lane] + beta[2 * lane], 0.f);
    float y1 = fmaxf((a1 - mu) * rstd * gamma[2 * lane + 1] + beta[2 * lane + 1], 0.f);
    unsigned pk = (unsigned)f2bf(y0) | ((unsigned)f2bf(y1) << 16);
    __builtin_nontemporal_store(pk, &h1b[(size_t)wid * 64 + lane]);
}

// Layer 2 propagation + bias. One wave per node; 2 edges per gather
// instruction (es = lane>>5 picks edge 2j+es, u = lane&31 is the uint chunk
// of the 64-feature row). 16-edge batches -> 8 gathers in flight per lane.
__global__ __launch_bounds__(256) void prop_out(const unsigned* __restrict__ h2b,
                                                const int* __restrict__ offs,
                                                const unsigned* __restrict__ epk,
                                                const float* __restrict__ dinv,
                                                const float* __restrict__ b2,
                                                float* __restrict__ out, int n) {
    int wid = __builtin_amdgcn_readfirstlane((blockIdx.x * blockDim.x + threadIdx.x) >> 6);
    int lane = threadIdx.x & 63;
    if (wid >= n) return;
    int es = lane >> 5, u = lane & 31;
    float di = dinv[wid];
    float a0 = 0.f, a1 = 0.f;
    if (es == 0) {
        unsigned self = h2b[(size_t)wid * 32 + u];
        a0 = bfLo(self) * di * di;
        a1 = bfHi(self) * di * di;
    }

    int s0 = offs[wid], s1 = offs[wid + 1];
    if (s0 < s1) {
        const u32x4* ep4 = (const u32x4*)(epk + s0);
        int nb16 = (s1 - s0) >> 4;
        u32x4 d0 = __builtin_nontemporal_load(ep4);
        u32x4 d1 = __builtin_nontemporal_load(ep4 + 1);
        u32x4 d2 = __builtin_nontemporal_load(ep4 + 2);
        u32x4 d3 = __builtin_nontemporal_load(ep4 + 3);
        for (int b = 0; b < nb16; ++b) {
            unsigned dd0 = es ? d0.y : d0.x;
            unsigned dd1 = es ? d0.w : d0.z;
            unsigned dd2 = es ? d1.y : d1.x;
            unsigned dd3 = es ? d1.w : d1.z;
            unsigned dd4 = es ? d2.y : d2.x;
            unsigned dd5 = es ? d2.w : d2.z;
            unsigned dd6 = es ? d3.y : d3.x;
            unsigned dd7 = es ? d3.w : d3.z;
            unsigned g0 = h2b[(size_t)(dd0 >> 16) * 32 + u];
            unsigned g1 = h2b[(size_t)(dd1 >> 16) * 32 + u];
            unsigned g2 = h2b[(size_t)(dd2 >> 16) * 32 + u];
            unsigned g3 = h2b[(size_t)(dd3 >> 16) * 32 + u];
            unsigned g4 = h2b[(size_t)(dd4 >> 16) * 32 + u];
            unsigned g5 = h2b[(size_t)(dd5 >> 16) * 32 + u];
            unsigned g6 = h2b[(size_t)(dd6 >> 16) * 32 + u];
            unsigned g7 = h2b[(size_t)(dd7 >> 16) * 32 + u];
            float w0 = bfLo(dd0), w1 = bfLo(dd1), w2 = bfLo(dd2), w3 = bfLo(dd3);
            float w4 = bfLo(dd4), w5 = bfLo(dd5), w6 = bfLo(dd6), w7 = bfLo(dd7);
            int bn = (b + 1 < nb16) ? b + 1 : 0;
            d0 = __builtin_nontemporal_load(ep4 + 4 * bn);
            d1 = __builtin_nontemporal_load(ep4 + 4 * bn + 1);
            d2 = __builtin_nontemporal_load(ep4 + 4 * bn + 2);
            d3 = __builtin_nontemporal_load(ep4 + 4 * bn + 3);
            a0 = fmaf(bfLo(g0), w0, a0); a1 = fmaf(bfHi(g0), w0, a1);
            a0 = fmaf(bfLo(g1), w1, a0); a1 = fmaf(bfHi(g1), w1, a1);
            a0 = fmaf(bfLo(g2), w2, a0); a1 = fmaf(bfHi(g2), w2, a1);
            a0 = fmaf(bfLo(g3), w3, a0); a1 = fmaf(bfHi(g3), w3, a1);
            a0 = fmaf(bfLo(g4), w4, a0); a1 = fmaf(bfHi(g4), w4, a1);
            a0 = fmaf(bfLo(g5), w5, a0); a1 = fmaf(bfHi(g5), w5, a1);
            a0 = fmaf(bfLo(g6), w6, a0); a1 = fmaf(bfHi(g6), w6, a1);
            a0 = fmaf(bfLo(g7), w7, a0); a1 = fmaf(bfHi(g7), w7, a1);
        }
    }

    a0 += __shfl_xor(a0, 32);
    a1 += __shfl_xor(a1, 32);
    if (es == 0) {
        f32x2 o; o.x = a0 + b2[2 * u]; o.y = a1 + b2[2 * u + 1];
        __builtin_nontemporal_store(o, &((f32x2*)out)[(size_t)wid * 32 + u]);
    }
}

extern "C" void kernel_launch(void* const* d_in, const int* in_sizes, int n_in,
                              void* d_out, int out_size, void* d_ws, size_t ws_size,
                              hipStream_t stream) {
    const float* x     = (const float*)d_in[0];
    const int*   ei    = (const int*)d_in[1];
    const float* W1    = (const float*)d_in[2];
    const float* b1    = (const float*)d_in[3];
    const float* gam   = (const float*)d_in[4];
    const float* bet   = (const float*)d_in[5];
    const float* W2    = (const float*)d_in[6];
    const float* b2    = (const float*)d_in[7];
    float* out = (float*)d_out;

    int n = in_sizes[0] / 128;   // 50000  (must stay < 65536 for packed src)
    int e = in_sizes[1] / 2;     // 800000
    const int* src = ei;
    const int* dst = ei + e;
    size_t ecap = (size_t)e + 16 * (size_t)n;   // padded CSR capacity

    char* p = (char*)d_ws;
    auto alloc = [&](size_t bytes) {
        void* q = (void*)p;
        p += (bytes + 255) & ~(size_t)255;
        return q;
    };
    int*            cnt  = (int*)alloc((size_t)n * 4);
    int*            offs = (int*)alloc((size_t)(n + 1) * 4);
    int*            rank = (int*)alloc((size_t)e * 4);
    float*          dinv = (float*)alloc((size_t)n * 4);
    int*            incl = (int*)alloc((size_t)n * 4);
    int*            bsum = (int*)alloc(64 * 4);
    unsigned*       epk  = (unsigned*)alloc(ecap * 4);
    unsigned*       h0b  = (unsigned*)alloc((size_t)n * 64 * 4);  // bf16 [n][128]
    unsigned*       h1b  = (unsigned*)alloc((size_t)n * 64 * 4);  // bf16 [n][128]
    unsigned short* W1t  = (unsigned short*)alloc(128 * 128 * 2);
    unsigned short* W2t  = (unsigned short*)alloc(64 * 128 * 2);

    // Layer-2 table [n][32] aliases h0b (h0b dead after prop_ln).
    unsigned* h2b = h0b;

    int nb = (n + 1023) / 1024;  // 49 blocks for n=50000
    int gb = (n + 63) / 64;      // 782 gemm blocks; 4*gb = 3128 >= fb = 3125

    cvt_wi<<<(n + 255) / 256, 256, 0, stream>>>(W1, W2, W1t, W2t, cnt, n);
    count_k<<<(e + 255) / 256, 256, 0, stream>>>(dst, cnt, rank, e);
    scan1_k<<<nb, 1024, 0, stream>>>(cnt, incl, bsum, dinv, n);
    scan3_k<<<nb, 1024, 0, stream>>>(cnt, incl, bsum, offs, epk, nb, n);
    fill_gemm1_k<<<gb * 5, 256, 0, stream>>>(x, (const uint4*)W1t,
                                             (unsigned short*)h0b, n, gb,
                                             src, dst, rank, offs, dinv, epk, e);
    prop_ln<<<(n + 3) / 4, 256, 0, stream>>>(h0b, offs, epk, dinv, b1, gam, bet, h1b, n);
    gemm2_k<<<gb, 256, 0, stream>>>(h1b, (const uint4*)W2t,
                                    (unsigned short*)h2b, n);
    prop_out<<<(n + 3) / 4, 256, 0, stream>>>(h2b, offs, epk, dinv, b2, out, n);
}

// Round 20
// 158.656 us; speedup vs baseline: 2.0590x; 1.0181x over previous
//
#include <hip/hip_runtime.h>

// ---------------------------------------------------------------------------
// GCN 2-layer: h1 = relu(LN(Ahat @ (x W1) + b1)); out = Ahat @ (h1 W2) + b2
// Ahat = D^-1/2 (A+I) D^-1/2, CSR built on-device each call (no feature atomics)
// R1: hierarchical scan. R2: LDS-tiled gemm. R3: pipelined gathers, bf16 table.
// R4: 4B edge payload. R6/7: packed (src<<16|bf16 w) payload, NT streams.
// R8: MFMA gemm. R9/10: padded CSR buckets, 16B descriptor batches.
// R11/12: named scalars (PromoteAlloca-to-LDS fix). R14: folded scan (163.7).
// R16: 16-edge batches neutral (MSHR-saturated). R17: gemm1||fill grid-mix
//   (157.0 = best so far).
// FAILED & DO-NOT-RETRY: R13 lookback scan (serial atomic chain);
//   R5/R15 XCD feature-sharding (gathers latency-bound); R18 atomic-append
//   partition scatter (cursor chains + append thrash); R19 NT store on the
//   random epk scatter (no-allocate -> per-store partial-line HBM writeback,
//   WRITE 38->41MB) — NT is for streams, never scatters.
// R20: single-variable isolation: R17's regular scatter store + 1:4
//   gemm:fill block interleave (both workload types co-resident for the
//   whole fused dispatch). If >= 157, R17 is the plateau.
// ---------------------------------------------------------------------------

typedef float f32x2 __attribute__((ext_vector_type(2)));
typedef float f32x4 __attribute__((ext_vector_type(4)));
typedef unsigned u32x4 __attribute__((ext_vector_type(4)));
typedef __bf16 bf16x8 __attribute__((ext_vector_type(8)));

__device__ __forceinline__ unsigned short f2bf(float f) {
    unsigned u = __float_as_uint(f);
    u += 0x7FFF + ((u >> 16) & 1);     // round-to-nearest-even
    return (unsigned short)(u >> 16);
}
__device__ __forceinline__ float bfLo(unsigned g) { return __uint_as_float(g << 16); }
__device__ __forceinline__ float bfHi(unsigned g) { return __uint_as_float(g & 0xFFFF0000u); }

// W transpose->bf16 + cnt zero. One dispatch.
__global__ __launch_bounds__(256) void cvt_wi(const float* __restrict__ W1,
                                              const float* __restrict__ W2,
                                              unsigned short* __restrict__ W1t,
                                              unsigned short* __restrict__ W2t,
                                              int* __restrict__ cnt, int n) {
    int id = blockIdx.x * 256 + threadIdx.x;
    if (id < 128 * 128) {
        int c = id >> 7, k = id & 127;
        W1t[id] = f2bf(W1[k * 128 + c]);
    } else if (id < 128 * 128 + 64 * 128) {
        int j = id - 128 * 128;
        int c = j >> 7, k = j & 127;
        W2t[j] = f2bf(W2[k * 64 + c]);
    }
    if (id < n) cnt[id] = 0;
}

// count + rank in one pass: rank = arrival order within dst bucket.
__global__ void count_k(const int* __restrict__ dst, int* __restrict__ cnt,
                        int* __restrict__ rank, int e) {
    int i = blockIdx.x * blockDim.x + threadIdx.x;
    if (i < e) {
        int r = atomicAdd(&cnt[dst[i]], 1);
        __builtin_nontemporal_store(r, &rank[i]);
    }
}

// Pass 1: per-block inclusive scan of ceil16(cnt) -> incl, block totals ->
// bsum; dinv computed here.
__global__ __launch_bounds__(1024) void scan1_k(const int* __restrict__ cnt,
                                                int* __restrict__ incl,
                                                int* __restrict__ bsum,
                                                float* __restrict__ dinv, int n) {
    __shared__ int lds[1024];
    int t = threadIdx.x;
    int i = blockIdx.x * 1024 + t;
    int c = (i < n) ? cnt[i] : 0;
    int v = (i < n) ? ((c + 15) & ~15) : 0;      // padded bucket size
    lds[t] = v;
    __syncthreads();
#pragma unroll
    for (int d = 1; d < 1024; d <<= 1) {
        int u = (t >= d) ? lds[t - d] : 0;
        __syncthreads();
        lds[t] += u;
        __syncthreads();
    }
    if (i < n) {
        incl[i] = lds[t];
        dinv[i] = rsqrtf((float)(c + 1));        // deg includes self loop
    }
    if (t == 1023) bsum[blockIdx.x] = lds[1023];
}

// Pass 2: offs (exclusive padded prefix), sentinel, pad-slot zeroing.
// Wave 0 re-scans bsum (nb <= 64) locally via shfl_up -> no 2nd scan dispatch.
__global__ __launch_bounds__(1024) void scan3_k(const int* __restrict__ cnt,
                                                const int* __restrict__ incl,
                                                const int* __restrict__ bsum,
                                                int* __restrict__ offs,
                                                unsigned* __restrict__ epk,
                                                int nb, int n) {
    __shared__ int sP;
    int t = threadIdx.x, bid = blockIdx.x;
    if (t < 64) {
        int raw = (t < nb) ? bsum[t] : 0;
        int v = raw;
#pragma unroll
        for (int d = 1; d < 64; d <<= 1) {
            int u = __shfl_up(v, d);
            if (t >= d) v += u;
        }
        if (t == bid) sP = v - raw;    // exclusive prefix of this block
    }
    __syncthreads();
    int i = bid * 1024 + t;
    if (i >= n) return;
    int c = cnt[i];
    int c16 = (c + 15) & ~15;
    int inc = sP + incl[i];            // inclusive padded prefix
    int ex = inc - c16;
    offs[i] = ex;
    for (int j = c; j < c16; ++j)      // zero pad slots (weight +0.0)
        __builtin_nontemporal_store(0u, &epk[ex + j]);
    if (i == n - 1) offs[n] = inc;
}

// Scatter packed (src<<16 | bf16(w)) into CSR slots. 4B payload, no atomics,
// REGULAR store (coalesces in L2 — NT proven wrong for scatters, R19).
__device__ __forceinline__ void dev_fill(const int* __restrict__ src,
                                         const int* __restrict__ dst,
                                         const int* __restrict__ rank,
                                         const int* __restrict__ offs,
                                         const float* __restrict__ dinv,
                                         unsigned* __restrict__ epk, int e, int bid) {
    int i = bid * 256 + threadIdx.x;
    if (i >= e) return;
    int s = src[i], d = dst[i];
    float w = dinv[s] * dinv[d];         // in (0,1], sign bit 0 -> bf16 fits 16b
    epk[offs[d] + rank[i]] = ((unsigned)s << 16) | (unsigned)f2bf(w);
}

// MFMA GEMM body: A (bf16 [n][128], or f32 converted during staging when CVT)
// @ Wt^T (bf16 [NT*16][128] k-contiguous) -> tab (bf16 [n][NT*16]).
// Block = 64 rows, 4 waves. D layout (m89): col = lane&15, row = 4*(lane>>4)+reg.
template<int NT, bool CVT>
__device__ __forceinline__ void dev_gemm(const void* __restrict__ Asrc,
                                         const uint4* __restrict__ Wt,
                                         unsigned short* __restrict__ tab,
                                         int n, int bid, uint4* As) {
    int t = threadIdx.x;
    int r0 = bid * 64;
    int rows = min(64, n - r0);
#pragma unroll
    for (int it = 0; it < 4; ++it) {
        int u = it * 256 + t;
        int row = u >> 4, s = u & 15;
        uint4 v = make_uint4(0u, 0u, 0u, 0u);
        if (row < rows) {
            if constexpr (CVT) {
                const float4* X4 = (const float4*)Asrc;
                float4 a = X4[(size_t)(r0 + row) * 32 + 2 * s];
                float4 b = X4[(size_t)(r0 + row) * 32 + 2 * s + 1];
                v.x = (unsigned)f2bf(a.x) | ((unsigned)f2bf(a.y) << 16);
                v.y = (unsigned)f2bf(a.z) | ((unsigned)f2bf(a.w) << 16);
                v.z = (unsigned)f2bf(b.x) | ((unsigned)f2bf(b.y) << 16);
                v.w = (unsigned)f2bf(b.z) | ((unsigned)f2bf(b.w) << 16);
            } else {
                v = ((const uint4*)Asrc)[(size_t)(r0 + row) * 16 + s];
            }
        }
        As[row * 16 + (s ^ (row & 7))] = v;
    }
    __syncthreads();

    int wv = t >> 6, lane = t & 63;
    int arow = lane & 15;            // A-row within stripe / B-col within tile
    int kg = lane >> 4;              // k-group (frags) / row-group (D)
    int lrow = wv * 16 + arow;

    f32x4 acc[NT];
    f32x4 z = {0.f, 0.f, 0.f, 0.f};
#pragma unroll
    for (int j = 0; j < NT; ++j) acc[j] = z;

#pragma unroll
    for (int ks = 0; ks < 4; ++ks) {
        bf16x8 a = __builtin_bit_cast(bf16x8,
                       As[lrow * 16 + ((ks * 4 + kg) ^ (arow & 7))]);
#pragma unroll
        for (int tl = 0; tl < NT; ++tl) {
            bf16x8 b = __builtin_bit_cast(bf16x8,
                           Wt[(size_t)(tl * 16 + arow) * 16 + ks * 4 + kg]);
            acc[tl] = __builtin_amdgcn_mfma_f32_16x16x32_bf16(a, b, acc[tl], 0, 0, 0);
        }
    }

    int grow0 = r0 + wv * 16 + 4 * kg;
#pragma unroll
    for (int r = 0; r < 4; ++r) {
        int grow = grow0 + r;
        if (grow < n) {
            unsigned short* rowp = tab + (size_t)grow * (NT * 16) + arow;
#pragma unroll
            for (int tl = 0; tl < NT; ++tl)
                rowp[tl * 16] = f2bf(acc[tl][r]);
        }
    }
}

// Mixed dispatch, 1:4 interleave (gb gemm : 4*gb >= fb fill blocks): both
// workload types co-resident from t=0 through the whole dispatch. Disjoint
// outputs; deps: gemm1 <- cvt_wi(W1t); fill <- scan1+scan3+count.
__global__ __launch_bounds__(256) void fill_gemm1_k(const float* __restrict__ x,
                                                    const uint4* __restrict__ W1t,
                                                    unsigned short* __restrict__ h0b,
                                                    int n, int gb,
                                                    const int* __restrict__ src,
                                                    const int* __restrict__ dst,
                                                    const int* __restrict__ rank,
                                                    const int* __restrict__ offs,
                                                    const float* __restrict__ dinv,
                                                    unsigned* __restrict__ epk, int e) {
    __shared__ uint4 As[64 * 16];   // 16 KB (gemm path only)
    int bid = blockIdx.x;
    int g = bid / 5, r = bid % 5;
    if (r == 0 && g < gb)
        dev_gemm<8, true>(x, W1t, h0b, n, g, As);
    else
        dev_fill(src, dst, rank, offs, dinv, epk, e, g * 4 + r - 1);
}

// gemm2: h1b bf16 @ W2t -> h2 bf16 table.
__global__ __launch_bounds__(256) void gemm2_k(const unsigned* __restrict__ h1b,
                                               const uint4* __restrict__ W2t,
                                               unsigned short* __restrict__ tab,
                                               int n) {
    __shared__ uint4 As[64 * 16];
    dev_gemm<4, false>(h1b, W2t, tab, n, blockIdx.x, As);
}

// Layer 1 propagation + bias + LayerNorm + ReLU. One wave per node, lane
// holds features {2*lane, 2*lane+1}. Buckets padded to x16: per iteration
// 4x 16B NT descriptor loads + 16 independent gathers in flight, all named
// scalars (no local arrays -> no PromoteAlloca-to-LDS).
__global__ __launch_bounds__(256) void prop_ln(const unsigned* __restrict__ h0b,
                                               const int* __restrict__ offs,
                                               const unsigned* __restrict__ epk,
                                               const float* __restrict__ dinv,
                                               const float* __restrict__ b1,
                                               const float* __restrict__ gamma,
                                               const float* __restrict__ beta,
                                               unsigned* __restrict__ h1b, int n) {
    int wid = __builtin_amdgcn_readfirstlane((blockIdx.x * blockDim.x + threadIdx.x) >> 6);
    int lane = threadIdx.x & 63;
    if (wid >= n) return;
    float di = dinv[wid];
    unsigned self = h0b[(size_t)wid * 64 + lane];
    float a0 = bfLo(self) * di * di;   // self loop, norm = dinv^2
    float a1 = bfHi(self) * di * di;

    int s0 = offs[wid], s1 = offs[wid + 1];
    if (s0 < s1) {
        const u32x4* ep4 = (const u32x4*)(epk + s0);   // 64B-aligned (offs % 16 == 0)
        int nb16 = (s1 - s0) >> 4;
        u32x4 d0 = __builtin_nontemporal_load(ep4);
        u32x4 d1 = __builtin_nontemporal_load(ep4 + 1);
        u32x4 d2 = __builtin_nontemporal_load(ep4 + 2);
        u32x4 d3 = __builtin_nontemporal_load(ep4 + 3);
        for (int b = 0; b < nb16; ++b) {
            unsigned g0  = h0b[(size_t)(d0.x >> 16) * 64 + lane];
            unsigned g1  = h0b[(size_t)(d0.y >> 16) * 64 + lane];
            unsigned g2  = h0b[(size_t)(d0.z >> 16) * 64 + lane];
            unsigned g3  = h0b[(size_t)(d0.w >> 16) * 64 + lane];
            unsigned g4  = h0b[(size_t)(d1.x >> 16) * 64 + lane];
            unsigned g5  = h0b[(size_t)(d1.y >> 16) * 64 + lane];
            unsigned g6  = h0b[(size_t)(d1.z >> 16) * 64 + lane];
            unsigned g7  = h0b[(size_t)(d1.w >> 16) * 64 + lane];
            unsigned g8  = h0b[(size_t)(d2.x >> 16) * 64 + lane];
            unsigned g9  = h0b[(size_t)(d2.y >> 16) * 64 + lane];
            unsigned g10 = h0b[(size_t)(d2.z >> 16) * 64 + lane];
            unsigned g11 = h0b[(size_t)(d2.w >> 16) * 64 + lane];
            unsigned g12 = h0b[(size_t)(d3.x >> 16) * 64 + lane];
            unsigned g13 = h0b[(size_t)(d3.y >> 16) * 64 + lane];
            unsigned g14 = h0b[(size_t)(d3.z >> 16) * 64 + lane];
            unsigned g15 = h0b[(size_t)(d3.w >> 16) * 64 + lane];
            float w0  = bfLo(d0.x), w1  = bfLo(d0.y), w2  = bfLo(d0.z), w3  = bfLo(d0.w);
            float w4  = bfLo(d1.x), w5  = bfLo(d1.y), w6  = bfLo(d1.z), w7  = bfLo(d1.w);
            float w8  = bfLo(d2.x), w9  = bfLo(d2.y), w10 = bfLo(d2.z), w11 = bfLo(d2.w);
            float w12 = bfLo(d3.x), w13 = bfLo(d3.y), w14 = bfLo(d3.z), w15 = bfLo(d3.w);
            int bn = (b + 1 < nb16) ? b + 1 : 0;       // wave-uniform select
            d0 = __builtin_nontemporal_load(ep4 + 4 * bn);
            d1 = __builtin_nontemporal_load(ep4 + 4 * bn + 1);
            d2 = __builtin_nontemporal_load(ep4 + 4 * bn + 2);
            d3 = __builtin_nontemporal_load(ep4 + 4 * bn + 3);
            a0 = fmaf(bfLo(g0),  w0,  a0); a1 = fmaf(bfHi(g0),  w0,  a1);
            a0 = fmaf(bfLo(g1),  w1,  a0); a1 = fmaf(bfHi(g1),  w1,  a1);
            a0 = fmaf(bfLo(g2),  w2,  a0); a1 = fmaf(bfHi(g2),  w2,  a1);
            a0 = fmaf(bfLo(g3),  w3,  a0); a1 = fmaf(bfHi(g3),  w3,  a1);
            a0 = fmaf(bfLo(g4),  w4,  a0); a1 = fmaf(bfHi(g4),  w4,  a1);
            a0 = fmaf(bfLo(g5),  w5,  a0); a1 = fmaf(bfHi(g5),  w5,  a1);
            a0 = fmaf(bfLo(g6),  w6,  a0); a1 = fmaf(bfHi(g6),  w6,  a1);
            a0 = fmaf(bfLo(g7),  w7,  a0); a1 = fmaf(bfHi(g7),  w7,  a1);
            a0 = fmaf(bfLo(g8),  w8,  a0); a1 = fmaf(bfHi(g8),  w8,  a1);
            a0 = fmaf(bfLo(g9),  w9,  a0); a1 = fmaf(bfHi(g9),  w9,  a1);
            a0 = fmaf(bfLo(g10), w10, a0); a1 = fmaf(bfHi(g10), w10, a1);
            a0 = fmaf(bfLo(g11), w11, a0); a1 = fmaf(bfHi(g11), w11, a1);
            a0 = fmaf(bfLo(g12), w12, a0); a1 = fmaf(bfHi(g12), w12, a1);
            a0 = fmaf(bfLo(g13), w13, a0); a1 = fmaf(bfHi(g13), w13, a1);
            a0 = fmaf(bfLo(g14), w14, a0); a1 = fmaf(bfHi(g14), w14, a1);
            a0 = fmaf(bfLo(g15), w15, a0); a1 = fmaf(bfHi(g15), w15, a1);
        }
    }

    a0 += b1[2 * lane];
    a1 += b1[2 * lane + 1];
    // LayerNorm over 128 features spread across the 64-lane wave
    float sum = a0 + a1, sq = a0 * a0 + a1 * a1;
#pragma unroll
    for (int off = 32; off > 0; off >>= 1) {
        sum += __shfl_xor(sum, off);
        sq  += __shfl_xor(sq, off);
    }
    float mu  = sum * (1.f / 128.f);
    float var = fmaxf(sq * (1.f / 128.f) - mu * mu, 0.f);
    float rstd = rsqrtf(var + 1e-6f);
    float y0 = fmaxf((a0 - mu) * rstd * gamma[2 * lane] + beta[2 * lane], 0.f);
    float y1 = fmaxf((a1 - mu) * rstd * gamma[2 * lane + 1] + beta[2 * lane + 1], 0.f);
    unsigned pk = (unsigned)f2bf(y0) | ((unsigned)f2bf(y1) << 16);
    __builtin_nontemporal_store(pk, &h1b[(size_t)wid * 64 + lane]);
}

// Layer 2 propagation + bias. One wave per node; 2 edges per gather
// instruction (es = lane>>5 picks edge 2j+es, u = lane&31 is the uint chunk
// of the 64-feature row). 16-edge batches -> 8 gathers in flight per lane.
__global__ __launch_bounds__(256) void prop_out(const unsigned* __restrict__ h2b,
                                                const int* __restrict__ offs,
                                                const unsigned* __restrict__ epk,
                                                const float* __restrict__ dinv,
                                                const float* __restrict__ b2,
                                                float* __restrict__ out, int n) {
    int wid = __builtin_amdgcn_readfirstlane((blockIdx.x * blockDim.x + threadIdx.x) >> 6);
    int lane = threadIdx.x & 63;
    if (wid >= n) return;
    int es = lane >> 5, u = lane & 31;
    float di = dinv[wid];
    float a0 = 0.f, a1 = 0.f;
    if (es == 0) {
        unsigned self = h2b[(size_t)wid * 32 + u];
        a0 = bfLo(self) * di * di;
        a1 = bfHi(self) * di * di;
    }

    int s0 = offs[wid], s1 = offs[wid + 1];
    if (s0 < s1) {
        const u32x4* ep4 = (const u32x4*)(epk + s0);
        int nb16 = (s1 - s0) >> 4;
        u32x4 d0 = __builtin_nontemporal_load(ep4);
        u32x4 d1 = __builtin_nontemporal_load(ep4 + 1);
        u32x4 d2 = __builtin_nontemporal_load(ep4 + 2);
        u32x4 d3 = __builtin_nontemporal_load(ep4 + 3);
        for (int b = 0; b < nb16; ++b) {
            unsigned dd0 = es ? d0.y : d0.x;
            unsigned dd1 = es ? d0.w : d0.z;
            unsigned dd2 = es ? d1.y : d1.x;
            unsigned dd3 = es ? d1.w : d1.z;
            unsigned dd4 = es ? d2.y : d2.x;
            unsigned dd5 = es ? d2.w : d2.z;
            unsigned dd6 = es ? d3.y : d3.x;
            unsigned dd7 = es ? d3.w : d3.z;
            unsigned g0 = h2b[(size_t)(dd0 >> 16) * 32 + u];
            unsigned g1 = h2b[(size_t)(dd1 >> 16) * 32 + u];
            unsigned g2 = h2b[(size_t)(dd2 >> 16) * 32 + u];
            unsigned g3 = h2b[(size_t)(dd3 >> 16) * 32 + u];
            unsigned g4 = h2b[(size_t)(dd4 >> 16) * 32 + u];
            unsigned g5 = h2b[(size_t)(dd5 >> 16) * 32 + u];
            unsigned g6 = h2b[(size_t)(dd6 >> 16) * 32 + u];
            unsigned g7 = h2b[(size_t)(dd7 >> 16) * 32 + u];
            float w0 = bfLo(dd0), w1 = bfLo(dd1), w2 = bfLo(dd2), w3 = bfLo(dd3);
            float w4 = bfLo(dd4), w5 = bfLo(dd5), w6 = bfLo(dd6), w7 = bfLo(dd7);
            int bn = (b + 1 < nb16) ? b + 1 : 0;
            d0 = __builtin_nontemporal_load(ep4 + 4 * bn);
            d1 = __builtin_nontemporal_load(ep4 + 4 * bn + 1);
            d2 = __builtin_nontemporal_load(ep4 + 4 * bn + 2);
            d3 = __builtin_nontemporal_load(ep4 + 4 * bn + 3);
            a0 = fmaf(bfLo(g0), w0, a0); a1 = fmaf(bfHi(g0), w0, a1);
            a0 = fmaf(bfLo(g1), w1, a0); a1 = fmaf(bfHi(g1), w1, a1);
            a0 = fmaf(bfLo(g2), w2, a0); a1 = fmaf(bfHi(g2), w2, a1);
            a0 = fmaf(bfLo(g3), w3, a0); a1 = fmaf(bfHi(g3), w3, a1);
            a0 = fmaf(bfLo(g4), w4, a0); a1 = fmaf(bfHi(g4), w4, a1);
            a0 = fmaf(bfLo(g5), w5, a0); a1 = fmaf(bfHi(g5), w5, a1);
            a0 = fmaf(bfLo(g6), w6, a0); a1 = fmaf(bfHi(g6), w6, a1);
            a0 = fmaf(bfLo(g7), w7, a0); a1 = fmaf(bfHi(g7), w7, a1);
        }
    }

    a0 += __shfl_xor(a0, 32);
    a1 += __shfl_xor(a1, 32);
    if (es == 0) {
        f32x2 o; o.x = a0 + b2[2 * u]; o.y = a1 + b2[2 * u + 1];
        __builtin_nontemporal_store(o, &((f32x2*)out)[(size_t)wid * 32 + u]);
    }
}

extern "C" void kernel_launch(void* const* d_in, const int* in_sizes, int n_in,
                              void* d_out, int out_size, void* d_ws, size_t ws_size,
                              hipStream_t stream) {
    const float* x     = (const float*)d_in[0];
    const int*   ei    = (const int*)d_in[1];
    const float* W1    = (const float*)d_in[2];
    const float* b1    = (const float*)d_in[3];
    const float* gam   = (const float*)d_in[4];
    const float* bet   = (const float*)d_in[5];
    const float* W2    = (const float*)d_in[6];
    const float* b2    = (const float*)d_in[7];
    float* out = (float*)d_out;

    int n = in_sizes[0] / 128;   // 50000  (must stay < 65536 for packed src)
    int e = in_sizes[1] / 2;     // 800000
    const int* src = ei;
    const int* dst = ei + e;
    size_t ecap = (size_t)e + 16 * (size_t)n;   // padded CSR capacity

    char* p = (char*)d_ws;
    auto alloc = [&](size_t bytes) {
        void* q = (void*)p;
        p += (bytes + 255) & ~(size_t)255;
        return q;
    };
    int*            cnt  = (int*)alloc((size_t)n * 4);
    int*            offs = (int*)alloc((size_t)(n + 1) * 4);
    int*            rank = (int*)alloc((size_t)e * 4);
    float*          dinv = (float*)alloc((size_t)n * 4);
    int*            incl = (int*)alloc((size_t)n * 4);
    int*            bsum = (int*)alloc(64 * 4);
    unsigned*       epk  = (unsigned*)alloc(ecap * 4);
    unsigned*       h0b  = (unsigned*)alloc((size_t)n * 64 * 4);  // bf16 [n][128]
    unsigned*       h1b  = (unsigned*)alloc((size_t)n * 64 * 4);  // bf16 [n][128]
    unsigned short* W1t  = (unsigned short*)alloc(128 * 128 * 2);
    unsigned short* W2t  = (unsigned short*)alloc(64 * 128 * 2);

    // Layer-2 table [n][32] aliases h0b (h0b dead after prop_ln).
    unsigned* h2b = h0b;

    int nb = (n + 1023) / 1024;  // 49 blocks for n=50000
    int gb = (n + 63) / 64;      // 782 gemm blocks; 4*gb = 3128 >= fb = 3125

    cvt_wi<<<(n + 255) / 256, 256, 0, stream>>>(W1, W2, W1t, W2t, cnt, n);
    count_k<<<(e + 255) / 256, 256, 0, stream>>>(dst, cnt, rank, e);
    scan1_k<<<nb, 1024, 0, stream>>>(cnt, incl, bsum, dinv, n);
    scan3_k<<<nb, 1024, 0, stream>>>(cnt, incl, bsum, offs, epk, nb, n);
    fill_gemm1_k<<<gb * 5, 256, 0, stream>>>(x, (const uint4*)W1t,
                                             (unsigned short*)h0b, n, gb,
                                             src, dst, rank, offs, dinv, epk, e);
    prop_ln<<<(n + 3) / 4, 256, 0, stream>>>(h0b, offs, epk, dinv, b1, gam, bet, h1b, n);
    gemm2_k<<<gb, 256, 0, stream>>>(h1b, (const uint4*)W2t,
                                    (unsigned short*)h2b, n);
    prop_out<<<(n + 3) / 4, 256, 0, stream>>>(h2b, offs, epk, dinv, b2, out, n);
}

// Round 21
// 157.666 us; speedup vs baseline: 2.0719x; 1.0063x over previous
//
#include <hip/hip_runtime.h>

// ---------------------------------------------------------------------------
// GCN 2-layer: h1 = relu(LN(Ahat @ (x W1) + b1)); out = Ahat @ (h1 W2) + b2
// Ahat = D^-1/2 (A+I) D^-1/2, CSR built on-device each call (no feature atomics)
// R1: hierarchical scan. R2: LDS-tiled gemm. R3: pipelined gathers, bf16 table.
// R4: 4B edge payload. R6/7: packed (src<<16|bf16 w) payload, NT streams.
// R8: MFMA gemm. R9/10: padded CSR buckets, 16B descriptor batches.
// R11/12: named scalars (PromoteAlloca-to-LDS fix). R14: folded scan (163.7).
// R16: 16-edge batches neutral (MSHR-saturated). R17: gemm1||fill grid-mix,
//   gemm-first mapping (157.0 = best). R20: 1:4 interleave neutral (158.7).
// FAILED & DO-NOT-RETRY: R13 lookback scan (serial atomic chain);
//   R5/R15 XCD feature-sharding (gathers latency-bound); R18 atomic-append
//   partition scatter; R19 NT store on random scatter (partial-line HBM
//   writeback). fp8 tables rejected: error budget (~3% rel >> bf16's 0.4%)
//   would exceed the 0.0447 absmax threshold.
// R21: exact revert to R17's fused-dispatch mapping (best measured).
//   Plateau: gathers coalesced+MSHR-saturated, scatter physically minimal,
//   gemms at stream floors, dispatch chain minimized.
// ---------------------------------------------------------------------------

typedef float f32x2 __attribute__((ext_vector_type(2)));
typedef float f32x4 __attribute__((ext_vector_type(4)));
typedef unsigned u32x4 __attribute__((ext_vector_type(4)));
typedef __bf16 bf16x8 __attribute__((ext_vector_type(8)));

__device__ __forceinline__ unsigned short f2bf(float f) {
    unsigned u = __float_as_uint(f);
    u += 0x7FFF + ((u >> 16) & 1);     // round-to-nearest-even
    return (unsigned short)(u >> 16);
}
__device__ __forceinline__ float bfLo(unsigned g) { return __uint_as_float(g << 16); }
__device__ __forceinline__ float bfHi(unsigned g) { return __uint_as_float(g & 0xFFFF0000u); }

// W transpose->bf16 + cnt zero. One dispatch.
__global__ __launch_bounds__(256) void cvt_wi(const float* __restrict__ W1,
                                              const float* __restrict__ W2,
                                              unsigned short* __restrict__ W1t,
                                              unsigned short* __restrict__ W2t,
                                              int* __restrict__ cnt, int n) {
    int id = blockIdx.x * 256 + threadIdx.x;
    if (id < 128 * 128) {
        int c = id >> 7, k = id & 127;
        W1t[id] = f2bf(W1[k * 128 + c]);
    } else if (id < 128 * 128 + 64 * 128) {
        int j = id - 128 * 128;
        int c = j >> 7, k = j & 127;
        W2t[j] = f2bf(W2[k * 64 + c]);
    }
    if (id < n) cnt[id] = 0;
}

// count + rank in one pass: rank = arrival order within dst bucket.
__global__ void count_k(const int* __restrict__ dst, int* __restrict__ cnt,
                        int* __restrict__ rank, int e) {
    int i = blockIdx.x * blockDim.x + threadIdx.x;
    if (i < e) {
        int r = atomicAdd(&cnt[dst[i]], 1);
        __builtin_nontemporal_store(r, &rank[i]);
    }
}

// Pass 1: per-block inclusive scan of ceil16(cnt) -> incl, block totals ->
// bsum; dinv computed here.
__global__ __launch_bounds__(1024) void scan1_k(const int* __restrict__ cnt,
                                                int* __restrict__ incl,
                                                int* __restrict__ bsum,
                                                float* __restrict__ dinv, int n) {
    __shared__ int lds[1024];
    int t = threadIdx.x;
    int i = blockIdx.x * 1024 + t;
    int c = (i < n) ? cnt[i] : 0;
    int v = (i < n) ? ((c + 15) & ~15) : 0;      // padded bucket size
    lds[t] = v;
    __syncthreads();
#pragma unroll
    for (int d = 1; d < 1024; d <<= 1) {
        int u = (t >= d) ? lds[t - d] : 0;
        __syncthreads();
        lds[t] += u;
        __syncthreads();
    }
    if (i < n) {
        incl[i] = lds[t];
        dinv[i] = rsqrtf((float)(c + 1));        // deg includes self loop
    }
    if (t == 1023) bsum[blockIdx.x] = lds[1023];
}

// Pass 2: offs (exclusive padded prefix), sentinel, pad-slot zeroing.
// Wave 0 re-scans bsum (nb <= 64) locally via shfl_up -> no 2nd scan dispatch.
__global__ __launch_bounds__(1024) void scan3_k(const int* __restrict__ cnt,
                                                const int* __restrict__ incl,
                                                const int* __restrict__ bsum,
                                                int* __restrict__ offs,
                                                unsigned* __restrict__ epk,
                                                int nb, int n) {
    __shared__ int sP;
    int t = threadIdx.x, bid = blockIdx.x;
    if (t < 64) {
        int raw = (t < nb) ? bsum[t] : 0;
        int v = raw;
#pragma unroll
        for (int d = 1; d < 64; d <<= 1) {
            int u = __shfl_up(v, d);
            if (t >= d) v += u;
        }
        if (t == bid) sP = v - raw;    // exclusive prefix of this block
    }
    __syncthreads();
    int i = bid * 1024 + t;
    if (i >= n) return;
    int c = cnt[i];
    int c16 = (c + 15) & ~15;
    int inc = sP + incl[i];            // inclusive padded prefix
    int ex = inc - c16;
    offs[i] = ex;
    for (int j = c; j < c16; ++j)      // zero pad slots (weight +0.0)
        __builtin_nontemporal_store(0u, &epk[ex + j]);
    if (i == n - 1) offs[n] = inc;
}

// Scatter packed (src<<16 | bf16(w)) into CSR slots. 4B payload, no atomics,
// REGULAR store (coalesces in L2 — NT proven wrong for scatters, R19).
__device__ __forceinline__ void dev_fill(const int* __restrict__ src,
                                         const int* __restrict__ dst,
                                         const int* __restrict__ rank,
                                         const int* __restrict__ offs,
                                         const float* __restrict__ dinv,
                                         unsigned* __restrict__ epk, int e, int bid) {
    int i = bid * 256 + threadIdx.x;
    if (i >= e) return;
    int s = src[i], d = dst[i];
    float w = dinv[s] * dinv[d];         // in (0,1], sign bit 0 -> bf16 fits 16b
    epk[offs[d] + rank[i]] = ((unsigned)s << 16) | (unsigned)f2bf(w);
}

// MFMA GEMM body: A (bf16 [n][128], or f32 converted during staging when CVT)
// @ Wt^T (bf16 [NT*16][128] k-contiguous) -> tab (bf16 [n][NT*16]).
// Block = 64 rows, 4 waves. D layout (m89): col = lane&15, row = 4*(lane>>4)+reg.
template<int NT, bool CVT>
__device__ __forceinline__ void dev_gemm(const void* __restrict__ Asrc,
                                         const uint4* __restrict__ Wt,
                                         unsigned short* __restrict__ tab,
                                         int n, int bid, uint4* As) {
    int t = threadIdx.x;
    int r0 = bid * 64;
    int rows = min(64, n - r0);
#pragma unroll
    for (int it = 0; it < 4; ++it) {
        int u = it * 256 + t;
        int row = u >> 4, s = u & 15;
        uint4 v = make_uint4(0u, 0u, 0u, 0u);
        if (row < rows) {
            if constexpr (CVT) {
                const float4* X4 = (const float4*)Asrc;
                float4 a = X4[(size_t)(r0 + row) * 32 + 2 * s];
                float4 b = X4[(size_t)(r0 + row) * 32 + 2 * s + 1];
                v.x = (unsigned)f2bf(a.x) | ((unsigned)f2bf(a.y) << 16);
                v.y = (unsigned)f2bf(a.z) | ((unsigned)f2bf(a.w) << 16);
                v.z = (unsigned)f2bf(b.x) | ((unsigned)f2bf(b.y) << 16);
                v.w = (unsigned)f2bf(b.z) | ((unsigned)f2bf(b.w) << 16);
            } else {
                v = ((const uint4*)Asrc)[(size_t)(r0 + row) * 16 + s];
            }
        }
        As[row * 16 + (s ^ (row & 7))] = v;
    }
    __syncthreads();

    int wv = t >> 6, lane = t & 63;
    int arow = lane & 15;            // A-row within stripe / B-col within tile
    int kg = lane >> 4;              // k-group (frags) / row-group (D)
    int lrow = wv * 16 + arow;

    f32x4 acc[NT];
    f32x4 z = {0.f, 0.f, 0.f, 0.f};
#pragma unroll
    for (int j = 0; j < NT; ++j) acc[j] = z;

#pragma unroll
    for (int ks = 0; ks < 4; ++ks) {
        bf16x8 a = __builtin_bit_cast(bf16x8,
                       As[lrow * 16 + ((ks * 4 + kg) ^ (arow & 7))]);
#pragma unroll
        for (int tl = 0; tl < NT; ++tl) {
            bf16x8 b = __builtin_bit_cast(bf16x8,
                           Wt[(size_t)(tl * 16 + arow) * 16 + ks * 4 + kg]);
            acc[tl] = __builtin_amdgcn_mfma_f32_16x16x32_bf16(a, b, acc[tl], 0, 0, 0);
        }
    }

    int grow0 = r0 + wv * 16 + 4 * kg;
#pragma unroll
    for (int r = 0; r < 4; ++r) {
        int grow = grow0 + r;
        if (grow < n) {
            unsigned short* rowp = tab + (size_t)grow * (NT * 16) + arow;
#pragma unroll
            for (int tl = 0; tl < NT; ++tl)
                rowp[tl * 16] = f2bf(acc[tl][r]);
        }
    }
}

// Fused dispatch, R17 mapping: blocks [0, gb) = gemm1; blocks [gb, ...) =
// fill. Disjoint outputs; deps: gemm1 <- cvt_wi(W1t); fill <- scan1+scan3+count.
__global__ __launch_bounds__(256) void fill_gemm1_k(const float* __restrict__ x,
                                                    const uint4* __restrict__ W1t,
                                                    unsigned short* __restrict__ h0b,
                                                    int n, int gb,
                                                    const int* __restrict__ src,
                                                    const int* __restrict__ dst,
                                                    const int* __restrict__ rank,
                                                    const int* __restrict__ offs,
                                                    const float* __restrict__ dinv,
                                                    unsigned* __restrict__ epk, int e) {
    __shared__ uint4 As[64 * 16];   // 16 KB (gemm path only)
    int bid = blockIdx.x;
    if (bid < gb)
        dev_gemm<8, true>(x, W1t, h0b, n, bid, As);
    else
        dev_fill(src, dst, rank, offs, dinv, epk, e, bid - gb);
}

// gemm2: h1b bf16 @ W2t -> h2 bf16 table.
__global__ __launch_bounds__(256) void gemm2_k(const unsigned* __restrict__ h1b,
                                               const uint4* __restrict__ W2t,
                                               unsigned short* __restrict__ tab,
                                               int n) {
    __shared__ uint4 As[64 * 16];
    dev_gemm<4, false>(h1b, W2t, tab, n, blockIdx.x, As);
}

// Layer 1 propagation + bias + LayerNorm + ReLU. One wave per node, lane
// holds features {2*lane, 2*lane+1}. Buckets padded to x16: per iteration
// 4x 16B NT descriptor loads + 16 independent gathers in flight, all named
// scalars (no local arrays -> no PromoteAlloca-to-LDS).
__global__ __launch_bounds__(256) void prop_ln(const unsigned* __restrict__ h0b,
                                               const int* __restrict__ offs,
                                               const unsigned* __restrict__ epk,
                                               const float* __restrict__ dinv,
                                               const float* __restrict__ b1,
                                               const float* __restrict__ gamma,
                                               const float* __restrict__ beta,
                                               unsigned* __restrict__ h1b, int n) {
    int wid = __builtin_amdgcn_readfirstlane((blockIdx.x * blockDim.x + threadIdx.x) >> 6);
    int lane = threadIdx.x & 63;
    if (wid >= n) return;
    float di = dinv[wid];
    unsigned self = h0b[(size_t)wid * 64 + lane];
    float a0 = bfLo(self) * di * di;   // self loop, norm = dinv^2
    float a1 = bfHi(self) * di * di;

    int s0 = offs[wid], s1 = offs[wid + 1];
    if (s0 < s1) {
        const u32x4* ep4 = (const u32x4*)(epk + s0);   // 64B-aligned (offs % 16 == 0)
        int nb16 = (s1 - s0) >> 4;
        u32x4 d0 = __builtin_nontemporal_load(ep4);
        u32x4 d1 = __builtin_nontemporal_load(ep4 + 1);
        u32x4 d2 = __builtin_nontemporal_load(ep4 + 2);
        u32x4 d3 = __builtin_nontemporal_load(ep4 + 3);
        for (int b = 0; b < nb16; ++b) {
            unsigned g0  = h0b[(size_t)(d0.x >> 16) * 64 + lane];
            unsigned g1  = h0b[(size_t)(d0.y >> 16) * 64 + lane];
            unsigned g2  = h0b[(size_t)(d0.z >> 16) * 64 + lane];
            unsigned g3  = h0b[(size_t)(d0.w >> 16) * 64 + lane];
            unsigned g4  = h0b[(size_t)(d1.x >> 16) * 64 + lane];
            unsigned g5  = h0b[(size_t)(d1.y >> 16) * 64 + lane];
            unsigned g6  = h0b[(size_t)(d1.z >> 16) * 64 + lane];
            unsigned g7  = h0b[(size_t)(d1.w >> 16) * 64 + lane];
            unsigned g8  = h0b[(size_t)(d2.x >> 16) * 64 + lane];
            unsigned g9  = h0b[(size_t)(d2.y >> 16) * 64 + lane];
            unsigned g10 = h0b[(size_t)(d2.z >> 16) * 64 + lane];
            unsigned g11 = h0b[(size_t)(d2.w >> 16) * 64 + lane];
            unsigned g12 = h0b[(size_t)(d3.x >> 16) * 64 + lane];
            unsigned g13 = h0b[(size_t)(d3.y >> 16) * 64 + lane];
            unsigned g14 = h0b[(size_t)(d3.z >> 16) * 64 + lane];
            unsigned g15 = h0b[(size_t)(d3.w >> 16) * 64 + lane];
            float w0  = bfLo(d0.x), w1  = bfLo(d0.y), w2  = bfLo(d0.z), w3  = bfLo(d0.w);
            float w4  = bfLo(d1.x), w5  = bfLo(d1.y), w6  = bfLo(d1.z), w7  = bfLo(d1.w);
            float w8  = bfLo(d2.x), w9  = bfLo(d2.y), w10 = bfLo(d2.z), w11 = bfLo(d2.w);
            float w12 = bfLo(d3.x), w13 = bfLo(d3.y), w14 = bfLo(d3.z), w15 = bfLo(d3.w);
            int bn = (b + 1 < nb16) ? b + 1 : 0;       // wave-uniform select
            d0 = __builtin_nontemporal_load(ep4 + 4 * bn);
            d1 = __builtin_nontemporal_load(ep4 + 4 * bn + 1);
            d2 = __builtin_nontemporal_load(ep4 + 4 * bn + 2);
            d3 = __builtin_nontemporal_load(ep4 + 4 * bn + 3);
            a0 = fmaf(bfLo(g0),  w0,  a0); a1 = fmaf(bfHi(g0),  w0,  a1);
            a0 = fmaf(bfLo(g1),  w1,  a0); a1 = fmaf(bfHi(g1),  w1,  a1);
            a0 = fmaf(bfLo(g2),  w2,  a0); a1 = fmaf(bfHi(g2),  w2,  a1);
            a0 = fmaf(bfLo(g3),  w3,  a0); a1 = fmaf(bfHi(g3),  w3,  a1);
            a0 = fmaf(bfLo(g4),  w4,  a0); a1 = fmaf(bfHi(g4),  w4,  a1);
            a0 = fmaf(bfLo(g5),  w5,  a0); a1 = fmaf(bfHi(g5),  w5,  a1);
            a0 = fmaf(bfLo(g6),  w6,  a0); a1 = fmaf(bfHi(g6),  w6,  a1);
            a0 = fmaf(bfLo(g7),  w7,  a0); a1 = fmaf(bfHi(g7),  w7,  a1);
            a0 = fmaf(bfLo(g8),  w8,  a0); a1 = fmaf(bfHi(g8),  w8,  a1);
            a0 = fmaf(bfLo(g9),  w9,  a0); a1 = fmaf(bfHi(g9),  w9,  a1);
            a0 = fmaf(bfLo(g10), w10, a0); a1 = fmaf(bfHi(g10), w10, a1);
            a0 = fmaf(bfLo(g11), w11, a0); a1 = fmaf(bfHi(g11), w11, a1);
            a0 = fmaf(bfLo(g12), w12, a0); a1 = fmaf(bfHi(g12), w12, a1);
            a0 = fmaf(bfLo(g13), w13, a0); a1 = fmaf(bfHi(g13), w13, a1);
            a0 = fmaf(bfLo(g14), w14, a0); a1 = fmaf(bfHi(g14), w14, a1);
            a0 = fmaf(bfLo(g15), w15, a0); a1 = fmaf(bfHi(g15), w15, a1);
        }
    }

    a0 += b1[2 * lane];
    a1 += b1[2 * lane + 1];
    // LayerNorm over 128 features spread across the 64-lane wave
    float sum = a0 + a1, sq = a0 * a0 + a1 * a1;
#pragma unroll
    for (int off = 32; off > 0; off >>= 1) {
        sum += __shfl_xor(sum, off);
        sq  += __shfl_xor(sq, off);
    }
    float mu  = sum * (1.f / 128.f);
    float var = fmaxf(sq * (1.f / 128.f) - mu * mu, 0.f);
    float rstd = rsqrtf(var + 1e-6f);
    float y0 = fmaxf((a0 - mu) * rstd * gamma[2 * lane] + beta[2 * lane], 0.f);
    float y1 = fmaxf((a1 - mu) * rstd * gamma[2 * lane + 1] + beta[2 * lane + 1], 0.f);
    unsigned pk = (unsigned)f2bf(y0) | ((unsigned)f2bf(y1) << 16);
    __builtin_nontemporal_store(pk, &h1b[(size_t)wid * 64 + lane]);
}

// Layer 2 propagation + bias. One wave per node; 2 edges per gather
// instruction (es = lane>>5 picks edge 2j+es, u = lane&31 is the uint chunk
// of the 64-feature row). 16-edge batches -> 8 gathers in flight per lane.
__global__ __launch_bounds__(256) void prop_out(const unsigned* __restrict__ h2b,
                                                const int* __restrict__ offs,
                                                const unsigned* __restrict__ epk,
                                                const float* __restrict__ dinv,
                                                const float* __restrict__ b2,
                                                float* __restrict__ out, int n) {
    int wid = __builtin_amdgcn_readfirstlane((blockIdx.x * blockDim.x + threadIdx.x) >> 6);
    int lane = threadIdx.x & 63;
    if (wid >= n) return;
    int es = lane >> 5, u = lane & 31;
    float di = dinv[wid];
    float a0 = 0.f, a1 = 0.f;
    if (es == 0) {
        unsigned self = h2b[(size_t)wid * 32 + u];
        a0 = bfLo(self) * di * di;
        a1 = bfHi(self) * di * di;
    }

    int s0 = offs[wid], s1 = offs[wid + 1];
    if (s0 < s1) {
        const u32x4* ep4 = (const u32x4*)(epk + s0);
        int nb16 = (s1 - s0) >> 4;
        u32x4 d0 = __builtin_nontemporal_load(ep4);
        u32x4 d1 = __builtin_nontemporal_load(ep4 + 1);
        u32x4 d2 = __builtin_nontemporal_load(ep4 + 2);
        u32x4 d3 = __builtin_nontemporal_load(ep4 + 3);
        for (int b = 0; b < nb16; ++b) {
            unsigned dd0 = es ? d0.y : d0.x;
            unsigned dd1 = es ? d0.w : d0.z;
            unsigned dd2 = es ? d1.y : d1.x;
            unsigned dd3 = es ? d1.w : d1.z;
            unsigned dd4 = es ? d2.y : d2.x;
            unsigned dd5 = es ? d2.w : d2.z;
            unsigned dd6 = es ? d3.y : d3.x;
            unsigned dd7 = es ? d3.w : d3.z;
            unsigned g0 = h2b[(size_t)(dd0 >> 16) * 32 + u];
            unsigned g1 = h2b[(size_t)(dd1 >> 16) * 32 + u];
            unsigned g2 = h2b[(size_t)(dd2 >> 16) * 32 + u];
            unsigned g3 = h2b[(size_t)(dd3 >> 16) * 32 + u];
            unsigned g4 = h2b[(size_t)(dd4 >> 16) * 32 + u];
            unsigned g5 = h2b[(size_t)(dd5 >> 16) * 32 + u];
            unsigned g6 = h2b[(size_t)(dd6 >> 16) * 32 + u];
            unsigned g7 = h2b[(size_t)(dd7 >> 16) * 32 + u];
            float w0 = bfLo(dd0), w1 = bfLo(dd1), w2 = bfLo(dd2), w3 = bfLo(dd3);
            float w4 = bfLo(dd4), w5 = bfLo(dd5), w6 = bfLo(dd6), w7 = bfLo(dd7);
            int bn = (b + 1 < nb16) ? b + 1 : 0;
            d0 = __builtin_nontemporal_load(ep4 + 4 * bn);
            d1 = __builtin_nontemporal_load(ep4 + 4 * bn + 1);
            d2 = __builtin_nontemporal_load(ep4 + 4 * bn + 2);
            d3 = __builtin_nontemporal_load(ep4 + 4 * bn + 3);
            a0 = fmaf(bfLo(g0), w0, a0); a1 = fmaf(bfHi(g0), w0, a1);
            a0 = fmaf(bfLo(g1), w1, a0); a1 = fmaf(bfHi(g1), w1, a1);
            a0 = fmaf(bfLo(g2), w2, a0); a1 = fmaf(bfHi(g2), w2, a1);
            a0 = fmaf(bfLo(g3), w3, a0); a1 = fmaf(bfHi(g3), w3, a1);
            a0 = fmaf(bfLo(g4), w4, a0); a1 = fmaf(bfHi(g4), w4, a1);
            a0 = fmaf(bfLo(g5), w5, a0); a1 = fmaf(bfHi(g5), w5, a1);
            a0 = fmaf(bfLo(g6), w6, a0); a1 = fmaf(bfHi(g6), w6, a1);
            a0 = fmaf(bfLo(g7), w7, a0); a1 = fmaf(bfHi(g7), w7, a1);
        }
    }

    a0 += __shfl_xor(a0, 32);
    a1 += __shfl_xor(a1, 32);
    if (es == 0) {
        f32x2 o; o.x = a0 + b2[2 * u]; o.y = a1 + b2[2 * u + 1];
        __builtin_nontemporal_store(o, &((f32x2*)out)[(size_t)wid * 32 + u]);
    }
}

extern "C" void kernel_launch(void* const* d_in, const int* in_sizes, int n_in,
                              void* d_out, int out_size, void* d_ws, size_t ws_size,
                              hipStream_t stream) {
    const float* x     = (const float*)d_in[0];
    const int*   ei    = (const int*)d_in[1];
    const float* W1    = (const float*)d_in[2];
    const float* b1    = (const float*)d_in[3];
    const float* gam   = (const float*)d_in[4];
    const float* bet   = (const float*)d_in[5];
    const float* W2    = (const float*)d_in[6];
    const float* b2    = (const float*)d_in[7];
    float* out = (float*)d_out;

    int n = in_sizes[0] / 128;   // 50000  (must stay < 65536 for packed src)
    int e = in_sizes[1] / 2;     // 800000
    const int* src = ei;
    const int* dst = ei + e;
    size_t ecap = (size_t)e + 16 * (size_t)n;   // padded CSR capacity

    char* p = (char*)d_ws;
    auto alloc = [&](size_t bytes) {
        void* q = (void*)p;
        p += (bytes + 255) & ~(size_t)255;
        return q;
    };
    int*            cnt  = (int*)alloc((size_t)n * 4);
    int*            offs = (int*)alloc((size_t)(n + 1) * 4);
    int*            rank = (int*)alloc((size_t)e * 4);
    float*          dinv = (float*)alloc((size_t)n * 4);
    int*            incl = (int*)alloc((size_t)n * 4);
    int*            bsum = (int*)alloc(64 * 4);
    unsigned*       epk  = (unsigned*)alloc(ecap * 4);
    unsigned*       h0b  = (unsigned*)alloc((size_t)n * 64 * 4);  // bf16 [n][128]
    unsigned*       h1b  = (unsigned*)alloc((size_t)n * 64 * 4);  // bf16 [n][128]
    unsigned short* W1t  = (unsigned short*)alloc(128 * 128 * 2);
    unsigned short* W2t  = (unsigned short*)alloc(64 * 128 * 2);

    // Layer-2 table [n][32] aliases h0b (h0b dead after prop_ln).
    unsigned* h2b = h0b;

    int nb = (n + 1023) / 1024;  // 49 blocks for n=50000
    int gb = (n + 63) / 64;      // 782 gemm blocks
    int fb = (e + 255) / 256;    // 3125 fill blocks

    cvt_wi<<<(n + 255) / 256, 256, 0, stream>>>(W1, W2, W1t, W2t, cnt, n);
    count_k<<<(e + 255) / 256, 256, 0, stream>>>(dst, cnt, rank, e);
    scan1_k<<<nb, 1024, 0, stream>>>(cnt, incl, bsum, dinv, n);
    scan3_k<<<nb, 1024, 0, stream>>>(cnt, incl, bsum, offs, epk, nb, n);
    fill_gemm1_k<<<gb + fb, 256, 0, stream>>>(x, (const uint4*)W1t,
                                              (unsigned short*)h0b, n, gb,
                                              src, dst, rank, offs, dinv, epk, e);
    prop_ln<<<(n + 3) / 4, 256, 0, stream>>>(h0b, offs, epk, dinv, b1, gam, bet, h1b, n);
    gemm2_k<<<gb, 256, 0, stream>>>(h1b, (const uint4*)W2t,
                                    (unsigned short*)h2b, n);
    prop_out<<<(n + 3) / 4, 256, 0, stream>>>(h2b, offs, epk, dinv, b2, out, n);
}